// Round 14
// baseline (277.898 us; speedup 1.0000x reference)
//
#include <hip/hip_runtime.h>
#include <hip/hip_bf16.h>

#define N_NODES 100000
#define N_EDGESC 1600000
#define BATCH_B 16
#define NMAXC 4096
#define LATC 64
#define NBINS 391   // ceil(100000/256): 256 nodes per bin
#define NSB 256     // sort blocks
#define EPB ((N_EDGESC + NSB - 1) / NSB)  // 6250 edges per sort block
#define BIN_PAD 768 // worst-case per-bin alignment padding (256 nodes x 3)

// output layout offsets (flat f32)
#define OUT_NODES 0
#define OUT_EDGES 65536
#define OUT_FUEL  589824
#define OUT_ALT   917504
#define OUT_SLOPE 983040
#define OUT_MU    1048576
#define OUT_LG    1049600

typedef float f32x2 __attribute__((ext_vector_type(2)));
typedef float f32x4 __attribute__((ext_vector_type(4)));
typedef short bf16x8 __attribute__((ext_vector_type(8)));
union U4B { uint4 u; bf16x8 b; };

__device__ __forceinline__ unsigned short f2bf(float f) {
    unsigned int u = __float_as_uint(f);
    return (unsigned short)((u + 0x7FFFu + ((u >> 16) & 1u)) >> 16);  // RNE
}
__device__ __forceinline__ float bf2f(unsigned short h) {
    return __uint_as_float(((unsigned int)h) << 16);
}
__device__ __forceinline__ void f8acc(unsigned int u, float& a0, float& a1, float& a2, float& a3) {
    f32x2 lo = __builtin_amdgcn_cvt_pk_f32_fp8(u, false);
    f32x2 hi = __builtin_amdgcn_cvt_pk_f32_fp8(u, true);
    a0 += lo[0]; a1 += lo[1]; a2 += hi[0]; a3 += hi[1];
}
// decode 4 fp8 -> bf16x2 pair packed in 2 uints
__device__ __forceinline__ void f8_to_bf2(unsigned int u, unsigned int& q0, unsigned int& q1) {
    f32x2 lo = __builtin_amdgcn_cvt_pk_f32_fp8(u, false);
    f32x2 hi = __builtin_amdgcn_cvt_pk_f32_fp8(u, true);
    q0 = (unsigned int)f2bf(lo[0]) | ((unsigned int)f2bf(lo[1]) << 16);
    q1 = (unsigned int)f2bf(hi[0]) | ((unsigned int)f2bf(hi[1]) << 16);
}

// ---- CSR build via atomic-free counting sort by dst>>8 ----
__global__ __launch_bounds__(1024) void histA(const int* __restrict__ dst, int* __restrict__ hist) {
    __shared__ int h[NBINS];
    int b = blockIdx.x, t = threadIdx.x;
    for (int i = t; i < NBINS; i += 1024) h[i] = 0;
    __syncthreads();
    int e0 = b * EPB, e1 = min(e0 + EPB, N_EDGESC);
    for (int i = e0 + t; i < e1; i += 1024)
        atomicAdd(&h[dst[i] >> 8], 1);
    __syncthreads();
    for (int i = t; i < NBINS; i += 1024) hist[i * NSB + b] = h[i];
}

__global__ void scanB(int* __restrict__ hist, int* __restrict__ total) {
    __shared__ int sh[NSB];
    int j = blockIdx.x, t = threadIdx.x;  // 256 threads
    int v = hist[j * NSB + t];
    sh[t] = v; __syncthreads();
    for (int off = 1; off < NSB; off <<= 1) {
        int u = (t >= off) ? sh[t - off] : 0; __syncthreads();
        sh[t] += u; __syncthreads();
    }
    hist[j * NSB + t] = sh[t] - v;
    if (t == NSB - 1) total[j] = sh[t];
}

__global__ void scanC(const int* __restrict__ total, int* __restrict__ base) {
    __shared__ int sh[512];
    int t = threadIdx.x;
    int v = (t < NBINS) ? total[t] : 0;
    sh[t] = v; __syncthreads();
    for (int off = 1; off < 512; off <<= 1) {
        int u = (t >= off) ? sh[t - off] : 0; __syncthreads();
        sh[t] += u; __syncthreads();
    }
    if (t < NBINS) base[t] = sh[t] - v;
    if (t == NBINS - 1) base[NBINS] = sh[t];
}

__global__ __launch_bounds__(1024) void scatterD(const int* __restrict__ src, const int* __restrict__ dst,
                                                 const int* __restrict__ hist, const int* __restrict__ base,
                                                 unsigned int* __restrict__ sorted) {
    __shared__ int w0[NBINS];
    __shared__ int lc[NBINS];
    int b = blockIdx.x, t = threadIdx.x;
    for (int i = t; i < NBINS; i += 1024) {
        w0[i] = base[i] + hist[i * NSB + b];
        lc[i] = 0;
    }
    __syncthreads();
    int e0 = b * EPB, e1 = min(e0 + EPB, N_EDGESC);
    for (int i = e0 + t; i < e1; i += 1024) {
        int d = dst[i], s = src[i];
        int j = d >> 8;
        int r = atomicAdd(&lc[j], 1);
        sorted[w0[j] + r] = ((unsigned int)s << 8) | (d & 255);
    }
}

// compact CSR with 16B-aligned per-node lists + fused fp8 prescale of x
__global__ void csr_compact(const unsigned int* __restrict__ sorted, const int* __restrict__ base,
                            const float* __restrict__ x,
                            int* __restrict__ adj, int* __restrict__ offs,
                            int* __restrict__ cnt, float* __restrict__ dinv,
                            unsigned int* __restrict__ xs8, int N) {
    __shared__ int lc[256];
    __shared__ int cur[256];
    __shared__ int so4[256];
    int j = blockIdx.x, t = threadIdx.x;
    lc[t] = 0; cur[t] = 0;
    __syncthreads();
    int e0 = base[j], e1 = base[j + 1];
    for (int i = e0 + t; i < e1; i += 256)
        atomicAdd(&lc[sorted[i] & 255], 1);
    __syncthreads();
    int c4 = (lc[t] + 3) & ~3;   // align each list to 4 entries (16B)
    so4[t] = c4;
    __syncthreads();
    for (int off = 1; off < 256; off <<= 1) {
        int u = (t >= off) ? so4[t - off] : 0; __syncthreads();
        so4[t] += u; __syncthreads();
    }
    int mybase = base[j] + j * BIN_PAD + so4[t] - c4;  // exclusive, aligned
    __syncthreads();
    so4[t] = mybase;
    __syncthreads();
    for (int i = e0 + t; i < e1; i += 256) {
        unsigned int pk = sorted[i];
        int d = pk & 255;
        int r = atomicAdd(&cur[d], 1);
        adj[so4[d] + r] = (int)(pk >> 8);
    }
    int n = j * 256 + t;
    if (n < N) {
        int c = lc[t];
        cnt[n] = c;
        offs[n] = so4[t];
        float dv = rsqrtf((float)(c + 1));  // +1 = self loop
        dinv[n] = dv;
        float ds = dv * 64.f;
        const float* xr = &x[(size_t)n * 32];
        unsigned int q[8];
#pragma unroll
        for (int jj = 0; jj < 8; jj++) {
            float4 v = *(const float4*)&xr[jj * 4];
            unsigned int r8 = 0;
            r8 = __builtin_amdgcn_cvt_pk_fp8_f32(v.x * ds, v.y * ds, r8, false);
            r8 = __builtin_amdgcn_cvt_pk_fp8_f32(v.z * ds, v.w * ds, r8, true);
            q[jj] = r8;
        }
        *(uint4*)&xs8[(size_t)n * 8] = make_uint4(q[0], q[1], q[2], q[3]);
        *(uint4*)&xs8[(size_t)n * 8 + 4] = make_uint4(q[4], q[5], q[6], q[7]);
    }
}

// agg0 = S x : fp8 table [n][8] uints; 32 nodes per 256-thread block, 8 lanes/node
// output bf16 [n][32]
__global__ void agg_s32(const unsigned int* __restrict__ xs8, const int* __restrict__ cnt,
                        const int* __restrict__ offs, const int* __restrict__ adj,
                        const float* __restrict__ dinv, unsigned short* __restrict__ outb, int N) {
    int t = threadIdx.x;
    int sub = t >> 3, f = t & 7;
    int n = blockIdx.x * 32 + sub;
    if (n >= N) return;
    float s0 = 0.f, s1 = 0.f, s2 = 0.f, s3 = 0.f;
    f8acc(xs8[(size_t)n * 8 + f], s0, s1, s2, s3);
    int e = offs[n];
    int e1 = e + cnt[n];
    for (; e + 8 <= e1; e += 8) {
        int4 ia = *(const int4*)&adj[e];
        int4 ib = *(const int4*)&adj[e + 4];
        unsigned int u0 = xs8[(size_t)ia.x * 8 + f];
        unsigned int u1 = xs8[(size_t)ia.y * 8 + f];
        unsigned int u2 = xs8[(size_t)ia.z * 8 + f];
        unsigned int u3 = xs8[(size_t)ia.w * 8 + f];
        unsigned int u4 = xs8[(size_t)ib.x * 8 + f];
        unsigned int u5 = xs8[(size_t)ib.y * 8 + f];
        unsigned int u6 = xs8[(size_t)ib.z * 8 + f];
        unsigned int u7 = xs8[(size_t)ib.w * 8 + f];
        f8acc(u0, s0, s1, s2, s3); f8acc(u1, s0, s1, s2, s3);
        f8acc(u2, s0, s1, s2, s3); f8acc(u3, s0, s1, s2, s3);
        f8acc(u4, s0, s1, s2, s3); f8acc(u5, s0, s1, s2, s3);
        f8acc(u6, s0, s1, s2, s3); f8acc(u7, s0, s1, s2, s3);
    }
    if (e + 4 <= e1) {
        int4 ia = *(const int4*)&adj[e];
        unsigned int u0 = xs8[(size_t)ia.x * 8 + f];
        unsigned int u1 = xs8[(size_t)ia.y * 8 + f];
        unsigned int u2 = xs8[(size_t)ia.z * 8 + f];
        unsigned int u3 = xs8[(size_t)ia.w * 8 + f];
        f8acc(u0, s0, s1, s2, s3); f8acc(u1, s0, s1, s2, s3);
        f8acc(u2, s0, s1, s2, s3); f8acc(u3, s0, s1, s2, s3);
        e += 4;
    }
    for (; e < e1; e++) f8acc(xs8[(size_t)adj[e] * 8 + f], s0, s1, s2, s3);
    float d = dinv[n] * (1.f / 64.f);
    ushort4 o;
    o.x = f2bf(s0 * d); o.y = f2bf(s1 * d); o.z = f2bf(s2 * d); o.w = f2bf(s3 * d);
    *(ushort4*)&outb[(size_t)n * 32 + f * 4] = o;
}

// XCD-sliced 128-feature aggregation over slice-major fp8 tables [4][N][8 uints].
// slice = (blockIdx&7)>>1 -> blocks of one slice land on 2 XCDs (round-robin dispatch);
// per-XCD gather working set = 3.2 MB < 4 MB L2. Correctness independent of mapping.
// OUT8: hB8 slice-major [4][N][8]; else bf16 row-major [n][128].
template <bool BIASRELU, bool OUT8>
__global__ __launch_bounds__(256) void agg128s(
    const unsigned int* __restrict__ tbl, const int* __restrict__ cnt,
    const int* __restrict__ offs, const int* __restrict__ adj,
    const float* __restrict__ dinv, const float* __restrict__ bias,
    void* __restrict__ outv, int N) {
    int t = threadIdx.x;
    int sub = t >> 3, f = t & 7;
    int xcd = blockIdx.x & 7;
    int slice = xcd >> 1;
    int chunk = (blockIdx.x >> 3) * 2 + (xcd & 1);
    int n = chunk * 32 + sub;
    if (n >= N) return;
    const unsigned int* ts = tbl + (size_t)slice * N * 8;
    float s0 = 0.f, s1 = 0.f, s2 = 0.f, s3 = 0.f;
    f8acc(ts[(size_t)n * 8 + f], s0, s1, s2, s3);
    int e = offs[n];
    int e1 = e + cnt[n];
    for (; e + 8 <= e1; e += 8) {
        int4 ia = *(const int4*)&adj[e];
        int4 ib = *(const int4*)&adj[e + 4];
        unsigned int u0 = ts[(size_t)ia.x * 8 + f];
        unsigned int u1 = ts[(size_t)ia.y * 8 + f];
        unsigned int u2 = ts[(size_t)ia.z * 8 + f];
        unsigned int u3 = ts[(size_t)ia.w * 8 + f];
        unsigned int u4 = ts[(size_t)ib.x * 8 + f];
        unsigned int u5 = ts[(size_t)ib.y * 8 + f];
        unsigned int u6 = ts[(size_t)ib.z * 8 + f];
        unsigned int u7 = ts[(size_t)ib.w * 8 + f];
        f8acc(u0, s0, s1, s2, s3); f8acc(u1, s0, s1, s2, s3);
        f8acc(u2, s0, s1, s2, s3); f8acc(u3, s0, s1, s2, s3);
        f8acc(u4, s0, s1, s2, s3); f8acc(u5, s0, s1, s2, s3);
        f8acc(u6, s0, s1, s2, s3); f8acc(u7, s0, s1, s2, s3);
    }
    if (e + 4 <= e1) {
        int4 ia = *(const int4*)&adj[e];
        unsigned int u0 = ts[(size_t)ia.x * 8 + f];
        unsigned int u1 = ts[(size_t)ia.y * 8 + f];
        unsigned int u2 = ts[(size_t)ia.z * 8 + f];
        unsigned int u3 = ts[(size_t)ia.w * 8 + f];
        f8acc(u0, s0, s1, s2, s3); f8acc(u1, s0, s1, s2, s3);
        f8acc(u2, s0, s1, s2, s3); f8acc(u3, s0, s1, s2, s3);
        e += 4;
    }
    for (; e < e1; e++) f8acc(ts[(size_t)adj[e] * 8 + f], s0, s1, s2, s3);
    float d = dinv[n] * (1.f / 32.f);
    float v0 = s0 * d, v1 = s1 * d, v2 = s2 * d, v3 = s3 * d;
    if (BIASRELU) {
        float4 bv = ((const float4*)bias)[slice * 8 + f];
        v0 = fmaxf(v0 + bv.x, 0.f); v1 = fmaxf(v1 + bv.y, 0.f);
        v2 = fmaxf(v2 + bv.z, 0.f); v3 = fmaxf(v3 + bv.w, 0.f);
    }
    if (OUT8) {
        unsigned int r = 0;
        r = __builtin_amdgcn_cvt_pk_fp8_f32(v0 * 32.f, v1 * 32.f, r, false);
        r = __builtin_amdgcn_cvt_pk_fp8_f32(v2 * 32.f, v3 * 32.f, r, true);
        ((unsigned int*)outv)[((size_t)slice * N + n) * 8 + f] = r;
    } else {
        ushort4 u;
        u.x = f2bf(v0); u.y = f2bf(v1); u.z = f2bf(v2); u.w = f2bf(v3);
        *(ushort4*)&((unsigned short*)outv)[(size_t)n * 128 + slice * 32 + f * 4] = u;
    }
}

// device helper: pack one B-fragment quad from f32 weight matrix
__device__ __forceinline__ void wfrag_write(const float* W, int F, int col, int k0,
                                            unsigned int* dst) {
    unsigned int q[4];
#pragma unroll
    for (int jj = 0; jj < 4; jj++) {
        float lo = W[(size_t)(k0 + 2 * jj) * F + col];
        float hi = W[(size_t)(k0 + 2 * jj + 1) * F + col];
        q[jj] = (unsigned int)f2bf(lo) | ((unsigned int)f2bf(hi) << 16);
    }
    *(uint4*)dst = make_uint4(q[0], q[1], q[2], q[3]);
}

// ---- mega-prep: batch_count + bias concats + head composition + weight fragments ----
__global__ void mega_prep(const int* __restrict__ batch,
                          const float* __restrict__ w1m, const float* __restrict__ w1l,
                          const float* __restrict__ b1m, const float* __restrict__ b1l,
                          const float* __restrict__ b3m, const float* __restrict__ b3l,
                          const float* __restrict__ w2m, const float* __restrict__ w2l,
                          const float* __restrict__ w3m, const float* __restrict__ w3l,
                          const float* __restrict__ nm_wo, const float* __restrict__ nm_bo,
                          const float* __restrict__ ex_w, const float* __restrict__ ex_b,
                          const float* __restrict__ fu_w, const float* __restrict__ fu_b,
                          const float* __restrict__ al_w, const float* __restrict__ al_b,
                          const float* __restrict__ sl_w, const float* __restrict__ sl_b,
                          const float* __restrict__ em_wo,
                          int* __restrict__ bcnt, float* __restrict__ bcat1,
                          float* __restrict__ bcat3, float* __restrict__ wtn,
                          float* __restrict__ bcn, float* __restrict__ wte,
                          unsigned int* __restrict__ wf1, unsigned int* __restrict__ wf2,
                          unsigned int* __restrict__ wf3) {
    int blk = blockIdx.x, t = threadIdx.x;
    if (blk == 0) {
        if (t < 128) bcat1[t] = (t < 64) ? b1m[t] : b1l[t - 64];
        else { int f = t - 128; bcat3[f] = (f < 64) ? b3m[f] : b3l[f - 64]; }
        if (t < BATCH_B) {
            int b = t;
            int lo = 0, hi = N_NODES;
            while (lo < hi) { int mid = (lo + hi) >> 1; if (batch[mid] < b) lo = mid + 1; else hi = mid; }
            int start = lo;
            lo = 0; hi = N_NODES;
            while (lo < hi) { int mid = (lo + hi) >> 1; if (batch[mid] <= b) lo = mid + 1; else hi = mid; }
            bcnt[b] = lo - start;
        }
    } else if (blk <= 9) {
        int idx = (blk - 1) * 256 + t;
        if (idx < 1024) {
            int j = idx >> 7, k = idx & 127;
            float s = 0.f;
            for (int m = 0; m < 128; m++) {
                float w = (j == 0) ? ex_w[m] : (j <= 5) ? fu_w[m * 5 + (j - 1)]
                         : (j == 6) ? al_w[m] : sl_w[m];
                s += nm_wo[k * 128 + m] * w;
            }
            wtn[j * 128 + k] = s;
        } else if (idx < 2048) {
            int i2 = idx - 1024;
            int j = i2 >> 7, k = i2 & 127;
            wte[j * 128 + k] = em_wo[k * 8 + j];
        } else if (idx < 2056) {
            int j = idx - 2048;
            float s = (j == 0) ? ex_b[0] : (j <= 5) ? fu_b[j - 1] : (j == 6) ? al_b[0] : sl_b[0];
            for (int m = 0; m < 128; m++) {
                float w = (j == 0) ? ex_w[m] : (j <= 5) ? fu_w[m * 5 + (j - 1)]
                         : (j == 6) ? al_w[m] : sl_w[m];
                s += nm_bo[m] * w;
            }
            bcn[j] = s;
        }
    } else if (blk <= 17) {     // wf1: K=32 (S=1), F=128 concat [w1m|w1l]
        if (t < 64) {
            int c = blk - 10;
            int col = c * 16 + (t & 15);
            int k0 = (t >> 4) * 8;
            unsigned int q[4];
#pragma unroll
            for (int jj = 0; jj < 4; jj++) {
                int ka = k0 + 2 * jj, kb = ka + 1;
                float lo = (col < 64) ? w1m[ka * 64 + col] : w1l[ka * 64 + col - 64];
                float hi = (col < 64) ? w1m[kb * 64 + col] : w1l[kb * 64 + col - 64];
                q[jj] = (unsigned int)f2bf(lo) | ((unsigned int)f2bf(hi) << 16);
            }
            *(uint4*)&wf1[((size_t)c * 64 + t) * 4] = make_uint4(q[0], q[1], q[2], q[3]);
        }
    } else if (blk <= 49) {     // wf2: K=64 (S=2), F=128 (C=8), y in {0,1}
        if (t < 64) {
            int bc = blk - 18;
            int c = bc % 8, s = (bc / 8) % 2, y = bc / 16;
            const float* W = y ? w2l : w2m;
            wfrag_write(W, 128, c * 16 + (t & 15), s * 32 + (t >> 4) * 8,
                        &wf2[((size_t)bc * 64 + t) * 4]);
        }
    } else {                    // wf3: K=128 (S=4), F=64 (C=4), y in {0,1}
        if (t < 64) {
            int bc = blk - 50;
            int c = bc % 4, s = (bc / 4) % 4, y = bc / 16;
            const float* W = y ? w3l : w3m;
            wfrag_write(W, 64, c * 16 + (t & 15), s * 32 + (t >> 4) * 8,
                        &wf3[((size_t)bc * 64 + t) * 4]);
        }
    }
}

// ---- MFMA conv (L1): hA8 slice-major [4][N][32B] = fp8x32( dinv*relu(A@W + bias) )
__global__ __launch_bounds__(256) void mfma_conv1(
    const unsigned short* __restrict__ inv, const unsigned int* __restrict__ wfrag,
    const float* __restrict__ bias, const float* __restrict__ dinv,
    unsigned int* __restrict__ outv, int N) {
    constexpr int C = 8;       // F=128
    constexpr int FP = 132;
    __shared__ unsigned short buf[4][16][FP];
    int t = threadIdx.x, lane = t & 63, wave = t >> 6;
    int n0 = blockIdx.x * 64 + wave * 16;

    f32x4 acc[C];
#pragma unroll
    for (int c = 0; c < C; c++) acc[c] = (f32x4)(0.f);

    int arow = n0 + (lane & 15);
    bool aok = arow < N;
    U4B af; af.u = make_uint4(0u, 0u, 0u, 0u);
    if (aok)
        af.u = *(const uint4*)(inv + (size_t)arow * 32 + (lane >> 4) * 8);
#pragma unroll
    for (int c = 0; c < C; c++) {
        U4B wb;
        wb.u = *(const uint4*)&wfrag[((size_t)c * 64 + lane) * 4];
        acc[c] = __builtin_amdgcn_mfma_f32_16x16x32_bf16(af.b, wb.b, acc[c], 0, 0, 0);
    }

#pragma unroll
    for (int c = 0; c < C; c++) {
        int col = c * 16 + (lane & 15);
        float bv = bias[col];
#pragma unroll
        for (int r = 0; r < 4; r++) {
            int row = (lane >> 4) * 4 + r;
            int n = n0 + row;
            float v = fmaxf(acc[c][r] + bv, 0.f) * dinv[min(n, N - 1)];
            buf[wave][row][col] = f2bf(v);
        }
    }
    __syncthreads();

    for (int i = t; i < 64 * 16; i += 256) {   // CPR = 128/8 = 16
        int row = i / 16;
        int f0 = (i % 16) * 8;
        int n = blockIdx.x * 64 + row;
        if (n >= N) continue;
        const unsigned short* bp = &buf[row >> 4][row & 15][f0];
        uint2 a = *(const uint2*)bp;
        uint2 b = *(const uint2*)(bp + 4);
        float e0 = __uint_as_float(a.x << 16), e1 = __uint_as_float(a.x & 0xFFFF0000u);
        float e2 = __uint_as_float(a.y << 16), e3 = __uint_as_float(a.y & 0xFFFF0000u);
        float e4 = __uint_as_float(b.x << 16), e5 = __uint_as_float(b.x & 0xFFFF0000u);
        float e6 = __uint_as_float(b.y << 16), e7 = __uint_as_float(b.y & 0xFFFF0000u);
        unsigned int r0 = 0, r1 = 0;
        r0 = __builtin_amdgcn_cvt_pk_fp8_f32(e0 * 32.f, e1 * 32.f, r0, false);
        r0 = __builtin_amdgcn_cvt_pk_fp8_f32(e2 * 32.f, e3 * 32.f, r0, true);
        r1 = __builtin_amdgcn_cvt_pk_fp8_f32(e4 * 32.f, e5 * 32.f, r1, false);
        r1 = __builtin_amdgcn_cvt_pk_fp8_f32(e6 * 32.f, e7 * 32.f, r1, true);
        // slice-major: slice = f0>>5, offset in row = f0&31
        *(uint2*)((unsigned char*)outv + ((size_t)(f0 >> 5) * N + n) * 32 + (f0 & 31))
            = make_uint2(r0, r1);
    }
}

// ---- fused L2+L3 conv: hB8 (slice-major) -> (L2, LDS) -> (L3) -> hD8 (slice-major)
__global__ __launch_bounds__(256) void conv23(
    const unsigned int* __restrict__ hB8, const unsigned int* __restrict__ wf2,
    const unsigned int* __restrict__ wf3, const float* __restrict__ b2m,
    const float* __restrict__ b2l, const float* __restrict__ dinv,
    unsigned int* __restrict__ hD8, int N) {
    __shared__ unsigned short hbuf[4][16][136];   // L2 out tile (wave-local)
    __shared__ unsigned short obuf[4][16][72];    // L3 out tile
    int t = threadIdx.x, lane = t & 63, wave = t >> 6;
    int y = blockIdx.y;
    int n0 = blockIdx.x * 64 + wave * 16;
    const float* bias = y ? b2l : b2m;
    const unsigned int* w2 = wf2 + (size_t)y * 2 * 8 * 64 * 4;
    const unsigned int* w3 = wf3 + (size_t)y * 4 * 4 * 64 * 4;

    f32x4 acc2[8];
#pragma unroll
    for (int c = 0; c < 8; c++) acc2[c] = (f32x4)(0.f);
    int arow = n0 + (lane & 15);
    bool aok = arow < N;
#pragma unroll
    for (int s = 0; s < 2; s++) {
        U4B af; af.u = make_uint4(0u, 0u, 0u, 0u);
        if (aok) {
            // slice-major read: slice = y*2+s, offset = (lane>>4)*8 bytes
            uint2 u = *(const uint2*)((const unsigned char*)hB8 +
                        ((size_t)(y * 2 + s) * N + arow) * 32 + (lane >> 4) * 8);
            f8_to_bf2(u.x, af.u.x, af.u.y);
            f8_to_bf2(u.y, af.u.z, af.u.w);
        }
#pragma unroll
        for (int c = 0; c < 8; c++) {
            U4B wb;
            wb.u = *(const uint4*)&w2[((size_t)(s * 8 + c) * 64 + lane) * 4];
            acc2[c] = __builtin_amdgcn_mfma_f32_16x16x32_bf16(af.b, wb.b, acc2[c], 0, 0, 0);
        }
    }
#pragma unroll
    for (int c = 0; c < 8; c++) {
        int col = c * 16 + (lane & 15);
        float bv = bias[col];
#pragma unroll
        for (int r = 0; r < 4; r++) {
            int row = (lane >> 4) * 4 + r;
            float v = fmaxf(acc2[c][r] * (1.f / 32.f) + bv, 0.f);
            hbuf[wave][row][col] = f2bf(v);
        }
    }
    // wave-local LDS write->read: same-wave DS ops are in-order; no block barrier needed

    f32x4 acc3[4];
#pragma unroll
    for (int c = 0; c < 4; c++) acc3[c] = (f32x4)(0.f);
#pragma unroll
    for (int s = 0; s < 4; s++) {
        U4B af;
        af.u = *(const uint4*)&hbuf[wave][lane & 15][s * 32 + (lane >> 4) * 8];
#pragma unroll
        for (int c = 0; c < 4; c++) {
            U4B wb;
            wb.u = *(const uint4*)&w3[((size_t)(s * 4 + c) * 64 + lane) * 4];
            acc3[c] = __builtin_amdgcn_mfma_f32_16x16x32_bf16(af.b, wb.b, acc3[c], 0, 0, 0);
        }
    }
#pragma unroll
    for (int c = 0; c < 4; c++) {
        int col = c * 16 + (lane & 15);
#pragma unroll
        for (int r = 0; r < 4; r++) {
            int row = (lane >> 4) * 4 + r;
            int n = n0 + row;
            float v = acc3[c][r] * dinv[min(n, N - 1)];
            obuf[wave][row][col] = f2bf(v);
        }
    }
    __syncthreads();
    for (int i = t; i < 64 * 8; i += 256) {   // F=64 -> 8 chunks/row
        int row = i / 8;
        int f0 = (i % 8) * 8;
        int n = blockIdx.x * 64 + row;
        if (n >= N) continue;
        const unsigned short* bp = &obuf[row >> 4][row & 15][f0];
        uint2 a = *(const uint2*)bp;
        uint2 b = *(const uint2*)(bp + 4);
        float e0 = __uint_as_float(a.x << 16), e1 = __uint_as_float(a.x & 0xFFFF0000u);
        float e2 = __uint_as_float(a.y << 16), e3 = __uint_as_float(a.y & 0xFFFF0000u);
        float e4 = __uint_as_float(b.x << 16), e5 = __uint_as_float(b.x & 0xFFFF0000u);
        float e6 = __uint_as_float(b.y << 16), e7 = __uint_as_float(b.y & 0xFFFF0000u);
        unsigned int r0 = 0, r1 = 0;
        r0 = __builtin_amdgcn_cvt_pk_fp8_f32(e0 * 32.f, e1 * 32.f, r0, false);
        r0 = __builtin_amdgcn_cvt_pk_fp8_f32(e2 * 32.f, e3 * 32.f, r0, true);
        r1 = __builtin_amdgcn_cvt_pk_fp8_f32(e4 * 32.f, e5 * 32.f, r1, false);
        r1 = __builtin_amdgcn_cvt_pk_fp8_f32(e6 * 32.f, e7 * 32.f, r1, true);
        // global feature = y*64 + f0 -> slice = (y*64+f0)>>5, offset = f0&31
        int F = y * 64 + f0;
        *(uint2*)((unsigned char*)hD8 + ((size_t)(F >> 5) * N + n) * 32 + (F & 31))
            = make_uint2(r0, r1);
    }
}

// parallel pooled sum: 4 waves/block, each wave reduces 16 rows (run-detected on sorted batch)
__global__ __launch_bounds__(256) void pool128(const unsigned int* __restrict__ h,
                                               const int* __restrict__ batch,
                                               float* __restrict__ sums, int n) {
    int t = threadIdx.x, lane = t & 63, wave = t >> 6;
    int r0 = blockIdx.x * 64 + wave * 16;
    if (r0 >= n) return;
    int r1 = min(r0 + 16, n);
    int cur = batch[r0];
    float a0 = 0.f, a1 = 0.f;
    for (int i = r0; i < r1; i++) {
        int b = batch[i];
        if (b != cur) {
            atomicAdd(&sums[cur * 128 + 2 * lane], a0);
            atomicAdd(&sums[cur * 128 + 2 * lane + 1], a1);
            a0 = a1 = 0.f; cur = b;
        }
        unsigned int u = h[(size_t)i * 64 + lane];
        a0 += __uint_as_float(u << 16);
        a1 += __uint_as_float(u & 0xFFFF0000u);
    }
    atomicAdd(&sums[cur * 128 + 2 * lane], a0);
    atomicAdd(&sums[cur * 128 + 2 * lane + 1], a1);
}

// finalize pool + zwi fused: 16 blocks x 128 threads
__global__ void finalize_zwi(const float* __restrict__ sums, const int* __restrict__ bcnt,
                             const float* __restrict__ nm_wi, const float* __restrict__ nm_bi,
                             const float* __restrict__ em_wi, const float* __restrict__ em_bi,
                             float* __restrict__ out, float* __restrict__ zwi_nm,
                             float* __restrict__ zwi_em) {
    __shared__ float zs[64];
    int b = blockIdx.x, t = threadIdx.x;
    float c = fmaxf((float)bcnt[b], 1.f);
    float v = sums[b * 128 + t] / c;
    if (t < 64) { out[OUT_MU + b * 64 + t] = v; zs[t] = v; }
    else out[OUT_LG + b * 64 + (t - 64)] = v;
    __syncthreads();
    float an = nm_bi[t], ae = em_bi[t];
    for (int k = 0; k < 64; k++) {
        float zv = zs[k];
        an += zv * nm_wi[k * 128 + t];
        ae += zv * em_wi[k * 128 + t];
    }
    zwi_nm[b * 128 + t] = an;
    zwi_em[b * 128 + t] = ae;
}

#define D3_ROWS 32

// decoder3: layer1+LN -> LDS; heads/edges as 128-len LDS dots (heads pre-composed)
__global__ __launch_bounds__(256) void decoder3(
    const float* __restrict__ zwi_nm, const float* __restrict__ zwi_em,
    const float* __restrict__ nm_wi, const float* __restrict__ em_wi,
    const float* __restrict__ nm_g, const float* __restrict__ nm_be,
    const float* __restrict__ em_g, const float* __restrict__ em_be,
    const float* __restrict__ wtn, const float* __restrict__ bcn,
    const float* __restrict__ wte, const float* __restrict__ em_bo,
    const float* __restrict__ pos_all,
    float* __restrict__ out) {
    __shared__ float sn[D3_ROWS][132];
    __shared__ float se[D3_ROWS][132];
    __shared__ float Wn[8][132];
    __shared__ float We[8][132];
    int t = threadIdx.x;
    int lane = t & 63, wave = t >> 6;
    int rowBase = blockIdx.x * D3_ROWS;
    int b = rowBase >> 12;
    int row0 = rowBase + wave * 8;

    for (int i = t; i < 1024; i += 256) {
        Wn[i >> 7][i & 127] = wtn[i];
        We[i >> 7][i & 127] = wte[i];
    }

    int f0 = lane, f1 = lane + 64;
    float zn0 = zwi_nm[b * 128 + f0], zn1 = zwi_nm[b * 128 + f1];
    float ze0 = zwi_em[b * 128 + f0], ze1 = zwi_em[b * 128 + f1];
    float wn64_0 = nm_wi[64 * 128 + f0], wn64_1 = nm_wi[64 * 128 + f1];
    float wn65_0 = nm_wi[65 * 128 + f0], wn65_1 = nm_wi[65 * 128 + f1];
    float we64_0 = em_wi[64 * 128 + f0], we64_1 = em_wi[64 * 128 + f1];
    float we65_0 = em_wi[65 * 128 + f0], we65_1 = em_wi[65 * 128 + f1];
    float gn0 = nm_g[f0], gn1 = nm_g[f1], bn0 = nm_be[f0], bn1 = nm_be[f1];
    float ge0 = em_g[f0], ge1 = em_g[f1], be0 = em_be[f0], be1 = em_be[f1];

#pragma unroll
    for (int r = 0; r < 8; r++) {
        int row = row0 + r, i = row & (NMAXC - 1);
        float px = pos_all[i * 2], py = pos_all[i * 2 + 1];
        float a0 = zn0 + px * wn64_0 + py * wn65_0;
        float a1 = zn1 + px * wn64_1 + py * wn65_1;
        float e0 = ze0 + px * we64_0 + py * we65_0;
        float e1 = ze1 + px * we64_1 + py * we65_1;
        float sm = a0 + a1, sq = a0 * a0 + a1 * a1;
        float sme = e0 + e1, sqe = e0 * e0 + e1 * e1;
#pragma unroll
        for (int d = 1; d < 64; d <<= 1) {
            sm += __shfl_xor(sm, d); sq += __shfl_xor(sq, d);
            sme += __shfl_xor(sme, d); sqe += __shfl_xor(sqe, d);
        }
        float mean = sm * (1.f / 128.f);
        float var = sq * (1.f / 128.f) - mean * mean;
        float rstd = rsqrtf(var + 1e-5f);
        int rl = wave * 8 + r;
        sn[rl][f0] = fmaxf((a0 - mean) * rstd * gn0 + bn0, 0.f);
        sn[rl][f1] = fmaxf((a1 - mean) * rstd * gn1 + bn1, 0.f);
        float meane = sme * (1.f / 128.f);
        float vare = sqe * (1.f / 128.f) - meane * meane;
        float rstde = rsqrtf(vare + 1e-5f);
        se[rl][f0] = fmaxf((e0 - meane) * rstde * ge0 + be0, 0.f);
        se[rl][f1] = fmaxf((e1 - meane) * rstde * ge1 + be1, 0.f);
    }
    __syncthreads();

    int rl = t >> 3, j = t & 7;
    float accn = 0.f, acce = 0.f;
#pragma unroll 8
    for (int k4 = 0; k4 < 128; k4 += 4) {
        float4 sv = *(const float4*)&sn[rl][k4];
        float4 wv = *(const float4*)&Wn[j][k4];
        float4 sev = *(const float4*)&se[rl][k4];
        float4 wev = *(const float4*)&We[j][k4];
        accn += sv.x * wv.x + sv.y * wv.y + sv.z * wv.z + sv.w * wv.w;
        acce += sev.x * wev.x + sev.y * wev.y + sev.z * wev.z + sev.w * wev.w;
    }
    int row = rowBase + rl;
    accn += bcn[j];
    if (j == 0)       out[OUT_NODES + row] = accn;
    else if (j <= 5)  out[OUT_FUEL + (size_t)row * 5 + (j - 1)] = accn;
    else if (j == 6)  out[OUT_ALT + row] = accn;
    else              out[OUT_SLOPE + row] = accn;
    out[OUT_EDGES + (size_t)row * 8 + j] = acce + em_bo[j];
}

extern "C" void kernel_launch(void* const* d_in, const int* in_sizes, int n_in,
                              void* d_out, int out_size, void* d_ws, size_t ws_size,
                              hipStream_t stream) {
    const float* x    = (const float*)d_in[0];
    const int* edge   = (const int*)d_in[1];
    const int* batch  = (const int*)d_in[2];
    const float* w1m = (const float*)d_in[3];  const float* b1m = (const float*)d_in[4];
    const float* w2m = (const float*)d_in[5];  const float* b2m = (const float*)d_in[6];
    const float* w3m = (const float*)d_in[7];  const float* b3m = (const float*)d_in[8];
    const float* w1l = (const float*)d_in[9];  const float* b1l = (const float*)d_in[10];
    const float* w2l = (const float*)d_in[11]; const float* b2l = (const float*)d_in[12];
    const float* w3l = (const float*)d_in[13]; const float* b3l = (const float*)d_in[14];
    const float* nm_wi = (const float*)d_in[15]; const float* nm_bi = (const float*)d_in[16];
    const float* nm_g  = (const float*)d_in[17]; const float* nm_be = (const float*)d_in[18];
    const float* nm_wo = (const float*)d_in[19]; const float* nm_bo = (const float*)d_in[20];
    const float* ex_w = (const float*)d_in[21]; const float* ex_b = (const float*)d_in[22];
    const float* fu_w = (const float*)d_in[23]; const float* fu_b = (const float*)d_in[24];
    const float* al_w = (const float*)d_in[25]; const float* al_b = (const float*)d_in[26];
    const float* sl_w = (const float*)d_in[27]; const float* sl_b = (const float*)d_in[28];
    const float* em_wi = (const float*)d_in[29]; const float* em_bi = (const float*)d_in[30];
    const float* em_g  = (const float*)d_in[31]; const float* em_be = (const float*)d_in[32];
    const float* em_wo = (const float*)d_in[33]; const float* em_bo = (const float*)d_in[34];
    const float* pos_all = (const float*)d_in[35];
    float* out = (float*)d_out;

    char* p = (char*)d_ws;
    auto alloc = [&](size_t bytes) -> void* {
        void* r = (void*)p;
        p += ((bytes + 255) / 256) * 256;
        return r;
    };
    int* cnt      = (int*)alloc((size_t)N_NODES * 4);
    int* offs     = (int*)alloc((size_t)N_NODES * 4);
    float* dinv   = (float*)alloc((size_t)N_NODES * 4);
    int* bcnt     = (int*)alloc(BATCH_B * 4);
    float* sums   = (float*)alloc(BATCH_B * 128 * 4);
    float* zwi_nm = (float*)alloc(BATCH_B * 128 * 4);
    float* zwi_em = (float*)alloc(BATCH_B * 128 * 4);
    float* bcat1  = (float*)alloc(128 * 4);
    float* bcat3  = (float*)alloc(128 * 4);
    float* wtn    = (float*)alloc(8 * 128 * 4);
    float* bcn    = (float*)alloc(8 * 4);
    float* wte    = (float*)alloc(8 * 128 * 4);
    unsigned int* wf1 = (unsigned int*)alloc((size_t)8 * 64 * 4 * 4);
    unsigned int* wf2 = (unsigned int*)alloc((size_t)32 * 64 * 4 * 4);
    unsigned int* wf3 = (unsigned int*)alloc((size_t)32 * 64 * 4 * 4);
    int* hist     = (int*)alloc((size_t)NBINS * NSB * 4);
    int* total    = (int*)alloc((size_t)NBINS * 4);
    int* base     = (int*)alloc((size_t)(NBINS + 1) * 4);
    unsigned int* sorted = (unsigned int*)alloc((size_t)N_EDGESC * 4);
    int* adj      = (int*)alloc((size_t)(N_EDGESC + NBINS * BIN_PAD + 256) * 4);
    unsigned int* xs8 = (unsigned int*)alloc((size_t)N_NODES * 8 * 4);
    unsigned short* agg0b = (unsigned short*)alloc((size_t)N_NODES * 32 * 2);
    unsigned int* hA8 = (unsigned int*)alloc((size_t)N_NODES * 32 * 4);   // slice-major (also hD8)
    unsigned int* hB8 = (unsigned int*)alloc((size_t)N_NODES * 32 * 4);   // slice-major
    unsigned short* final128 = (unsigned short*)alloc((size_t)N_NODES * 128 * 2);
    unsigned int* hD8 = hA8;  // hA8 dead after agg #1

    const int* srcp = edge;
    const int* dstp = edge + N_EDGESC;

    hipMemsetAsync(sums, 0, (size_t)BATCH_B * 128 * 4, stream);

    mega_prep<<<82, 256, 0, stream>>>(batch, w1m, w1l, b1m, b1l, b3m, b3l,
                                      w2m, w2l, w3m, w3l, nm_wo, nm_bo,
                                      ex_w, ex_b, fu_w, fu_b, al_w, al_b, sl_w, sl_b,
                                      em_wo, bcnt, bcat1, bcat3, wtn, bcn, wte,
                                      wf1, wf2, wf3);

    // ---- CSR build: atomic-free counting sort -> compact aligned CSR (+fused prescale) ----
    histA<<<NSB, 1024, 0, stream>>>(dstp, hist);
    scanB<<<NBINS, NSB, 0, stream>>>(hist, total);
    scanC<<<1, 512, 0, stream>>>(total, base);
    scatterD<<<NSB, 1024, 0, stream>>>(srcp, dstp, hist, base, sorted);
    csr_compact<<<NBINS, 256, 0, stream>>>(sorted, base, x, adj, offs, cnt, dinv, xs8, N_NODES);

    // agg0 = S x  (shared by both branches), fp8 table -> bf16 out
    agg_s32<<<(N_NODES + 31) / 32, 256, 0, stream>>>(xs8, cnt, offs, adj, dinv, agg0b, N_NODES);

    const int GB = (N_NODES + 63) / 64;            // 1563 row blocks
    const int NCHUNK = (N_NODES + 31) / 32;        // 3125
    const int AGG_GRID = ((NCHUNK + 1) / 2) * 8;   // 12504 (xcd-sliced)

    // L1 (fused mu|lg): hA8 (slice-major) = fp8x32( dinv * relu(agg0 @ [w1m|w1l] + bcat1) )
    mfma_conv1<<<GB, 256, 0, stream>>>(agg0b, wf1, bcat1, dinv, hA8, N_NODES);

    // agg #1 (XCD-sliced): hB8 (slice-major) = fp8x32( [S mu1 | S lg1] )
    agg128s<false, true><<<AGG_GRID, 256, 0, stream>>>(
        hA8, cnt, offs, adj, dinv, nullptr, hB8, N_NODES);

    // fused L2+L3: hD8 (slice-major) = fp8x32( dinv * ( relu(hB8@w2 + b2) @ w3 ) )
    conv23<<<dim3(GB, 2), 256, 0, stream>>>(hB8, wf2, wf3, b2m, b2l, dinv, hD8, N_NODES);

    // agg #2 (XCD-sliced): final128 = relu(dinv*(sum) + bcat3) -> bf16 [n][128]
    agg128s<true, false><<<AGG_GRID, 256, 0, stream>>>(
        hD8, cnt, offs, adj, dinv, bcat3, final128, N_NODES);

    pool128<<<GB, 256, 0, stream>>>((const unsigned int*)final128, batch, sums, N_NODES);
    finalize_zwi<<<BATCH_B, 128, 0, stream>>>(sums, bcnt, nm_wi, nm_bi, em_wi, em_bi,
                                              out, zwi_nm, zwi_em);

    decoder3<<<BATCH_B * NMAXC / D3_ROWS, 256, 0, stream>>>(
        zwi_nm, zwi_em, nm_wi, em_wi, nm_g, nm_be, em_g, em_be,
        wtn, bcn, wte, em_bo, pos_all, out);
}

// Round 15
// 257.199 us; speedup vs baseline: 1.0805x; 1.0805x over previous
//
#include <hip/hip_runtime.h>
#include <hip/hip_bf16.h>

#define N_NODES 100000
#define N_EDGESC 1600000
#define BATCH_B 16
#define NMAXC 4096
#define LATC 64
#define NBINS 391   // ceil(100000/256): 256 nodes per bin
#define NSB 256     // sort blocks
#define EPB ((N_EDGESC + NSB - 1) / NSB)  // 6250 edges per sort block
#define BIN_PAD 768 // worst-case per-bin alignment padding (256 nodes x 3)

// output layout offsets (flat f32)
#define OUT_NODES 0
#define OUT_EDGES 65536
#define OUT_FUEL  589824
#define OUT_ALT   917504
#define OUT_SLOPE 983040
#define OUT_MU    1048576
#define OUT_LG    1049600

typedef float f32x2 __attribute__((ext_vector_type(2)));
typedef float f32x4 __attribute__((ext_vector_type(4)));
typedef short bf16x8 __attribute__((ext_vector_type(8)));
union U4B { uint4 u; bf16x8 b; };

__device__ __forceinline__ unsigned short f2bf(float f) {
    unsigned int u = __float_as_uint(f);
    return (unsigned short)((u + 0x7FFFu + ((u >> 16) & 1u)) >> 16);  // RNE
}
__device__ __forceinline__ float bf2f(unsigned short h) {
    return __uint_as_float(((unsigned int)h) << 16);
}
__device__ __forceinline__ void f8acc(unsigned int u, float& a0, float& a1, float& a2, float& a3) {
    f32x2 lo = __builtin_amdgcn_cvt_pk_f32_fp8(u, false);
    f32x2 hi = __builtin_amdgcn_cvt_pk_f32_fp8(u, true);
    a0 += lo[0]; a1 += lo[1]; a2 += hi[0]; a3 += hi[1];
}
// decode 4 fp8 -> bf16x2 pair packed in 2 uints
__device__ __forceinline__ void f8_to_bf2(unsigned int u, unsigned int& q0, unsigned int& q1) {
    f32x2 lo = __builtin_amdgcn_cvt_pk_f32_fp8(u, false);
    f32x2 hi = __builtin_amdgcn_cvt_pk_f32_fp8(u, true);
    q0 = (unsigned int)f2bf(lo[0]) | ((unsigned int)f2bf(lo[1]) << 16);
    q1 = (unsigned int)f2bf(hi[0]) | ((unsigned int)f2bf(hi[1]) << 16);
}

// ---- CSR build via atomic-free counting sort by dst>>8 ----
__global__ __launch_bounds__(1024) void histA(const int* __restrict__ dst, int* __restrict__ hist) {
    __shared__ int h[NBINS];
    int b = blockIdx.x, t = threadIdx.x;
    for (int i = t; i < NBINS; i += 1024) h[i] = 0;
    __syncthreads();
    int e0 = b * EPB, e1 = min(e0 + EPB, N_EDGESC);
    for (int i = e0 + t; i < e1; i += 1024)
        atomicAdd(&h[dst[i] >> 8], 1);
    __syncthreads();
    for (int i = t; i < NBINS; i += 1024) hist[i * NSB + b] = h[i];
}

__global__ void scanB(int* __restrict__ hist, int* __restrict__ total) {
    __shared__ int sh[NSB];
    int j = blockIdx.x, t = threadIdx.x;  // 256 threads
    int v = hist[j * NSB + t];
    sh[t] = v; __syncthreads();
    for (int off = 1; off < NSB; off <<= 1) {
        int u = (t >= off) ? sh[t - off] : 0; __syncthreads();
        sh[t] += u; __syncthreads();
    }
    hist[j * NSB + t] = sh[t] - v;
    if (t == NSB - 1) total[j] = sh[t];
}

__global__ void scanC(const int* __restrict__ total, int* __restrict__ base) {
    __shared__ int sh[512];
    int t = threadIdx.x;
    int v = (t < NBINS) ? total[t] : 0;
    sh[t] = v; __syncthreads();
    for (int off = 1; off < 512; off <<= 1) {
        int u = (t >= off) ? sh[t - off] : 0; __syncthreads();
        sh[t] += u; __syncthreads();
    }
    if (t < NBINS) base[t] = sh[t] - v;
    if (t == NBINS - 1) base[NBINS] = sh[t];
}

__global__ __launch_bounds__(1024) void scatterD(const int* __restrict__ src, const int* __restrict__ dst,
                                                 const int* __restrict__ hist, const int* __restrict__ base,
                                                 unsigned int* __restrict__ sorted) {
    __shared__ int w0[NBINS];
    __shared__ int lc[NBINS];
    int b = blockIdx.x, t = threadIdx.x;
    for (int i = t; i < NBINS; i += 1024) {
        w0[i] = base[i] + hist[i * NSB + b];
        lc[i] = 0;
    }
    __syncthreads();
    int e0 = b * EPB, e1 = min(e0 + EPB, N_EDGESC);
    for (int i = e0 + t; i < e1; i += 1024) {
        int d = dst[i], s = src[i];
        int j = d >> 8;
        int r = atomicAdd(&lc[j], 1);
        sorted[w0[j] + r] = ((unsigned int)s << 8) | (d & 255);
    }
}

// compact CSR with 16B-aligned per-node lists + fused fp8 prescale of x
// oc[n] = (offs, cnt) packed -> single 8B header load in aggregation kernels
__global__ void csr_compact(const unsigned int* __restrict__ sorted, const int* __restrict__ base,
                            const float* __restrict__ x,
                            int* __restrict__ adj, int2* __restrict__ oc,
                            float* __restrict__ dinv, unsigned int* __restrict__ xs8, int N) {
    __shared__ int lc[256];
    __shared__ int cur[256];
    __shared__ int so4[256];
    int j = blockIdx.x, t = threadIdx.x;
    lc[t] = 0; cur[t] = 0;
    __syncthreads();
    int e0 = base[j], e1 = base[j + 1];
    for (int i = e0 + t; i < e1; i += 256)
        atomicAdd(&lc[sorted[i] & 255], 1);
    __syncthreads();
    int c4 = (lc[t] + 3) & ~3;   // align each list to 4 entries (16B)
    so4[t] = c4;
    __syncthreads();
    for (int off = 1; off < 256; off <<= 1) {
        int u = (t >= off) ? so4[t - off] : 0; __syncthreads();
        so4[t] += u; __syncthreads();
    }
    int mybase = base[j] + j * BIN_PAD + so4[t] - c4;  // exclusive, aligned
    __syncthreads();
    so4[t] = mybase;
    __syncthreads();
    for (int i = e0 + t; i < e1; i += 256) {
        unsigned int pk = sorted[i];
        int d = pk & 255;
        int r = atomicAdd(&cur[d], 1);
        adj[so4[d] + r] = (int)(pk >> 8);
    }
    int n = j * 256 + t;
    if (n < N) {
        int c = lc[t];
        oc[n] = make_int2(so4[t], c);
        float dv = rsqrtf((float)(c + 1));  // +1 = self loop
        dinv[n] = dv;
        float ds = dv * 64.f;
        const float* xr = &x[(size_t)n * 32];
        unsigned int q[8];
#pragma unroll
        for (int jj = 0; jj < 8; jj++) {
            float4 v = *(const float4*)&xr[jj * 4];
            unsigned int r8 = 0;
            r8 = __builtin_amdgcn_cvt_pk_fp8_f32(v.x * ds, v.y * ds, r8, false);
            r8 = __builtin_amdgcn_cvt_pk_fp8_f32(v.z * ds, v.w * ds, r8, true);
            q[jj] = r8;
        }
        *(uint4*)&xs8[(size_t)n * 8] = make_uint4(q[0], q[1], q[2], q[3]);
        *(uint4*)&xs8[(size_t)n * 8 + 4] = make_uint4(q[4], q[5], q[6], q[7]);
    }
}

// agg0 = S x : fp8 table [n][8] uints; 32 nodes per 256-thread block, 8 lanes/node
// output bf16 [n][32]
__global__ void agg_s32(const unsigned int* __restrict__ xs8, const int2* __restrict__ oc,
                        const int* __restrict__ adj, const float* __restrict__ dinv,
                        unsigned short* __restrict__ outb, int N) {
    int t = threadIdx.x;
    int sub = t >> 3, f = t & 7;
    int n = blockIdx.x * 32 + sub;
    if (n >= N) return;
    float s0 = 0.f, s1 = 0.f, s2 = 0.f, s3 = 0.f;
    f8acc(xs8[(size_t)n * 8 + f], s0, s1, s2, s3);
    int2 h = oc[n];
    int e = h.x, e1 = h.x + h.y;
    for (; e + 8 <= e1; e += 8) {
        int4 ia = *(const int4*)&adj[e];
        int4 ib = *(const int4*)&adj[e + 4];
        unsigned int u0 = xs8[(size_t)ia.x * 8 + f];
        unsigned int u1 = xs8[(size_t)ia.y * 8 + f];
        unsigned int u2 = xs8[(size_t)ia.z * 8 + f];
        unsigned int u3 = xs8[(size_t)ia.w * 8 + f];
        unsigned int u4 = xs8[(size_t)ib.x * 8 + f];
        unsigned int u5 = xs8[(size_t)ib.y * 8 + f];
        unsigned int u6 = xs8[(size_t)ib.z * 8 + f];
        unsigned int u7 = xs8[(size_t)ib.w * 8 + f];
        f8acc(u0, s0, s1, s2, s3); f8acc(u1, s0, s1, s2, s3);
        f8acc(u2, s0, s1, s2, s3); f8acc(u3, s0, s1, s2, s3);
        f8acc(u4, s0, s1, s2, s3); f8acc(u5, s0, s1, s2, s3);
        f8acc(u6, s0, s1, s2, s3); f8acc(u7, s0, s1, s2, s3);
    }
    if (e + 4 <= e1) {
        int4 ia = *(const int4*)&adj[e];
        unsigned int u0 = xs8[(size_t)ia.x * 8 + f];
        unsigned int u1 = xs8[(size_t)ia.y * 8 + f];
        unsigned int u2 = xs8[(size_t)ia.z * 8 + f];
        unsigned int u3 = xs8[(size_t)ia.w * 8 + f];
        f8acc(u0, s0, s1, s2, s3); f8acc(u1, s0, s1, s2, s3);
        f8acc(u2, s0, s1, s2, s3); f8acc(u3, s0, s1, s2, s3);
        e += 4;
    }
    for (; e < e1; e++) f8acc(xs8[(size_t)adj[e] * 8 + f], s0, s1, s2, s3);
    float d = dinv[n] * (1.f / 64.f);
    ushort4 o;
    o.x = f2bf(s0 * d); o.y = f2bf(s1 * d); o.z = f2bf(s2 * d); o.w = f2bf(s3 * d);
    *(ushort4*)&outb[(size_t)n * 32 + f * 4] = o;
}

// 128-dim fp8-table aggregation (table pre-scaled x32); 8 nodes/block, 32 lanes/node
template <bool BIASRELU, bool OUT8>
__global__ void agg128(const unsigned int* __restrict__ tbl, const int2* __restrict__ oc,
                       const int* __restrict__ adj, const float* __restrict__ dinv,
                       const float* __restrict__ bias, void* __restrict__ outv, int N) {
    int t = threadIdx.x;
    int sub = t >> 5, f = t & 31;
    int n = blockIdx.x * 8 + sub;
    if (n >= N) return;
    float s0 = 0.f, s1 = 0.f, s2 = 0.f, s3 = 0.f;
    f8acc(tbl[(size_t)n * 32 + f], s0, s1, s2, s3);
    int2 h = oc[n];
    int e = h.x, e1 = h.x + h.y;
    for (; e + 8 <= e1; e += 8) {
        int4 ia = *(const int4*)&adj[e];
        int4 ib = *(const int4*)&adj[e + 4];
        unsigned int u0 = tbl[(size_t)ia.x * 32 + f];
        unsigned int u1 = tbl[(size_t)ia.y * 32 + f];
        unsigned int u2 = tbl[(size_t)ia.z * 32 + f];
        unsigned int u3 = tbl[(size_t)ia.w * 32 + f];
        unsigned int u4 = tbl[(size_t)ib.x * 32 + f];
        unsigned int u5 = tbl[(size_t)ib.y * 32 + f];
        unsigned int u6 = tbl[(size_t)ib.z * 32 + f];
        unsigned int u7 = tbl[(size_t)ib.w * 32 + f];
        f8acc(u0, s0, s1, s2, s3); f8acc(u1, s0, s1, s2, s3);
        f8acc(u2, s0, s1, s2, s3); f8acc(u3, s0, s1, s2, s3);
        f8acc(u4, s0, s1, s2, s3); f8acc(u5, s0, s1, s2, s3);
        f8acc(u6, s0, s1, s2, s3); f8acc(u7, s0, s1, s2, s3);
    }
    if (e + 4 <= e1) {
        int4 ia = *(const int4*)&adj[e];
        unsigned int u0 = tbl[(size_t)ia.x * 32 + f];
        unsigned int u1 = tbl[(size_t)ia.y * 32 + f];
        unsigned int u2 = tbl[(size_t)ia.z * 32 + f];
        unsigned int u3 = tbl[(size_t)ia.w * 32 + f];
        f8acc(u0, s0, s1, s2, s3); f8acc(u1, s0, s1, s2, s3);
        f8acc(u2, s0, s1, s2, s3); f8acc(u3, s0, s1, s2, s3);
        e += 4;
    }
    for (; e < e1; e++) f8acc(tbl[(size_t)adj[e] * 32 + f], s0, s1, s2, s3);
    float d = dinv[n] * (1.f / 32.f);
    float v0 = s0 * d, v1 = s1 * d, v2 = s2 * d, v3 = s3 * d;
    if (BIASRELU) {
        float4 bv = *(const float4*)&bias[4 * f];
        v0 = fmaxf(v0 + bv.x, 0.f); v1 = fmaxf(v1 + bv.y, 0.f);
        v2 = fmaxf(v2 + bv.z, 0.f); v3 = fmaxf(v3 + bv.w, 0.f);
    }
    if (OUT8) {
        unsigned int r = 0;
        r = __builtin_amdgcn_cvt_pk_fp8_f32(v0 * 32.f, v1 * 32.f, r, false);
        r = __builtin_amdgcn_cvt_pk_fp8_f32(v2 * 32.f, v3 * 32.f, r, true);
        ((unsigned int*)outv)[(size_t)n * 32 + f] = r;
    } else {
        ushort4 u;
        u.x = f2bf(v0); u.y = f2bf(v1); u.z = f2bf(v2); u.w = f2bf(v3);
        *(ushort4*)&((unsigned short*)outv)[(size_t)n * 128 + 4 * f] = u;
    }
}

// device helper: pack one B-fragment quad from f32 weight matrix
__device__ __forceinline__ void wfrag_write(const float* W, int F, int col, int k0,
                                            unsigned int* dst) {
    unsigned int q[4];
#pragma unroll
    for (int jj = 0; jj < 4; jj++) {
        float lo = W[(size_t)(k0 + 2 * jj) * F + col];
        float hi = W[(size_t)(k0 + 2 * jj + 1) * F + col];
        q[jj] = (unsigned int)f2bf(lo) | ((unsigned int)f2bf(hi) << 16);
    }
    *(uint4*)dst = make_uint4(q[0], q[1], q[2], q[3]);
}

// ---- mega-prep: batch_count + bias concats + head composition + weight fragments ----
__global__ void mega_prep(const int* __restrict__ batch,
                          const float* __restrict__ w1m, const float* __restrict__ w1l,
                          const float* __restrict__ b1m, const float* __restrict__ b1l,
                          const float* __restrict__ b3m, const float* __restrict__ b3l,
                          const float* __restrict__ w2m, const float* __restrict__ w2l,
                          const float* __restrict__ w3m, const float* __restrict__ w3l,
                          const float* __restrict__ nm_wo, const float* __restrict__ nm_bo,
                          const float* __restrict__ ex_w, const float* __restrict__ ex_b,
                          const float* __restrict__ fu_w, const float* __restrict__ fu_b,
                          const float* __restrict__ al_w, const float* __restrict__ al_b,
                          const float* __restrict__ sl_w, const float* __restrict__ sl_b,
                          const float* __restrict__ em_wo,
                          int* __restrict__ bcnt, float* __restrict__ bcat1,
                          float* __restrict__ bcat3, float* __restrict__ wtn,
                          float* __restrict__ bcn, float* __restrict__ wte,
                          unsigned int* __restrict__ wf1, unsigned int* __restrict__ wf2,
                          unsigned int* __restrict__ wf3) {
    int blk = blockIdx.x, t = threadIdx.x;
    if (blk == 0) {
        if (t < 128) bcat1[t] = (t < 64) ? b1m[t] : b1l[t - 64];
        else { int f = t - 128; bcat3[f] = (f < 64) ? b3m[f] : b3l[f - 64]; }
        if (t < BATCH_B) {
            int b = t;
            int lo = 0, hi = N_NODES;
            while (lo < hi) { int mid = (lo + hi) >> 1; if (batch[mid] < b) lo = mid + 1; else hi = mid; }
            int start = lo;
            lo = 0; hi = N_NODES;
            while (lo < hi) { int mid = (lo + hi) >> 1; if (batch[mid] <= b) lo = mid + 1; else hi = mid; }
            bcnt[b] = lo - start;
        }
    } else if (blk <= 9) {
        int idx = (blk - 1) * 256 + t;
        if (idx < 1024) {
            int j = idx >> 7, k = idx & 127;
            float s = 0.f;
            for (int m = 0; m < 128; m++) {
                float w = (j == 0) ? ex_w[m] : (j <= 5) ? fu_w[m * 5 + (j - 1)]
                         : (j == 6) ? al_w[m] : sl_w[m];
                s += nm_wo[k * 128 + m] * w;
            }
            wtn[j * 128 + k] = s;
        } else if (idx < 2048) {
            int i2 = idx - 1024;
            int j = i2 >> 7, k = i2 & 127;
            wte[j * 128 + k] = em_wo[k * 8 + j];
        } else if (idx < 2056) {
            int j = idx - 2048;
            float s = (j == 0) ? ex_b[0] : (j <= 5) ? fu_b[j - 1] : (j == 6) ? al_b[0] : sl_b[0];
            for (int m = 0; m < 128; m++) {
                float w = (j == 0) ? ex_w[m] : (j <= 5) ? fu_w[m * 5 + (j - 1)]
                         : (j == 6) ? al_w[m] : sl_w[m];
                s += nm_bo[m] * w;
            }
            bcn[j] = s;
        }
    } else if (blk <= 17) {     // wf1: K=32 (S=1), F=128 concat [w1m|w1l]
        if (t < 64) {
            int c = blk - 10;
            int col = c * 16 + (t & 15);
            int k0 = (t >> 4) * 8;
            unsigned int q[4];
#pragma unroll
            for (int jj = 0; jj < 4; jj++) {
                int ka = k0 + 2 * jj, kb = ka + 1;
                float lo = (col < 64) ? w1m[ka * 64 + col] : w1l[ka * 64 + col - 64];
                float hi = (col < 64) ? w1m[kb * 64 + col] : w1l[kb * 64 + col - 64];
                q[jj] = (unsigned int)f2bf(lo) | ((unsigned int)f2bf(hi) << 16);
            }
            *(uint4*)&wf1[((size_t)c * 64 + t) * 4] = make_uint4(q[0], q[1], q[2], q[3]);
        }
    } else if (blk <= 49) {     // wf2: K=64 (S=2), F=128 (C=8), y in {0,1}
        if (t < 64) {
            int bc = blk - 18;
            int c = bc % 8, s = (bc / 8) % 2, y = bc / 16;
            const float* W = y ? w2l : w2m;
            wfrag_write(W, 128, c * 16 + (t & 15), s * 32 + (t >> 4) * 8,
                        &wf2[((size_t)bc * 64 + t) * 4]);
        }
    } else {                    // wf3: K=128 (S=4), F=64 (C=4), y in {0,1}
        if (t < 64) {
            int bc = blk - 50;
            int c = bc % 4, s = (bc / 4) % 4, y = bc / 16;
            const float* W = y ? w3l : w3m;
            wfrag_write(W, 64, c * 16 + (t & 15), s * 32 + (t >> 4) * 8,
                        &wf3[((size_t)bc * 64 + t) * 4]);
        }
    }
}

// ---- MFMA conv (L1): out[n] = fp8x32( dinv*relu(A@W + bias) ); bf16 input [n][32]
__global__ __launch_bounds__(256) void mfma_conv1(
    const unsigned short* __restrict__ inv, const unsigned int* __restrict__ wfrag,
    const float* __restrict__ bias, const float* __restrict__ dinv,
    unsigned int* __restrict__ outv, int N) {
    constexpr int C = 8;       // F=128
    constexpr int FP = 132;
    __shared__ unsigned short buf[4][16][FP];
    int t = threadIdx.x, lane = t & 63, wave = t >> 6;
    int n0 = blockIdx.x * 64 + wave * 16;

    f32x4 acc[C];
#pragma unroll
    for (int c = 0; c < C; c++) acc[c] = (f32x4)(0.f);

    int arow = n0 + (lane & 15);
    bool aok = arow < N;
    U4B af; af.u = make_uint4(0u, 0u, 0u, 0u);
    if (aok)
        af.u = *(const uint4*)(inv + (size_t)arow * 32 + (lane >> 4) * 8);
#pragma unroll
    for (int c = 0; c < C; c++) {
        U4B wb;
        wb.u = *(const uint4*)&wfrag[((size_t)c * 64 + lane) * 4];
        acc[c] = __builtin_amdgcn_mfma_f32_16x16x32_bf16(af.b, wb.b, acc[c], 0, 0, 0);
    }

#pragma unroll
    for (int c = 0; c < C; c++) {
        int col = c * 16 + (lane & 15);
        float bv = bias[col];
#pragma unroll
        for (int r = 0; r < 4; r++) {
            int row = (lane >> 4) * 4 + r;
            int n = n0 + row;
            float v = fmaxf(acc[c][r] + bv, 0.f) * dinv[min(n, N - 1)];
            buf[wave][row][col] = f2bf(v);
        }
    }
    __syncthreads();

    for (int i = t; i < 64 * 16; i += 256) {   // CPR = 128/8 = 16
        int row = i / 16;
        int f0 = (i % 16) * 8;
        int n = blockIdx.x * 64 + row;
        if (n >= N) continue;
        const unsigned short* bp = &buf[row >> 4][row & 15][f0];
        uint2 a = *(const uint2*)bp;
        uint2 b = *(const uint2*)(bp + 4);
        float e0 = __uint_as_float(a.x << 16), e1 = __uint_as_float(a.x & 0xFFFF0000u);
        float e2 = __uint_as_float(a.y << 16), e3 = __uint_as_float(a.y & 0xFFFF0000u);
        float e4 = __uint_as_float(b.x << 16), e5 = __uint_as_float(b.x & 0xFFFF0000u);
        float e6 = __uint_as_float(b.y << 16), e7 = __uint_as_float(b.y & 0xFFFF0000u);
        unsigned int r0 = 0, r1 = 0;
        r0 = __builtin_amdgcn_cvt_pk_fp8_f32(e0 * 32.f, e1 * 32.f, r0, false);
        r0 = __builtin_amdgcn_cvt_pk_fp8_f32(e2 * 32.f, e3 * 32.f, r0, true);
        r1 = __builtin_amdgcn_cvt_pk_fp8_f32(e4 * 32.f, e5 * 32.f, r1, false);
        r1 = __builtin_amdgcn_cvt_pk_fp8_f32(e6 * 32.f, e7 * 32.f, r1, true);
        *(uint2*)((unsigned char*)outv + (size_t)n * 128 + f0) = make_uint2(r0, r1);
    }
}

// ---- fused L2+L3 conv: hB8 -> (L2, LDS) -> (L3) -> hD8. Per branch y; 64 rows/block.
__global__ __launch_bounds__(256) void conv23(
    const unsigned int* __restrict__ hB8, const unsigned int* __restrict__ wf2,
    const unsigned int* __restrict__ wf3, const float* __restrict__ b2m,
    const float* __restrict__ b2l, const float* __restrict__ dinv,
    unsigned int* __restrict__ hD8, int N) {
    __shared__ unsigned short hbuf[4][16][136];   // L2 out tile (wave-local)
    __shared__ unsigned short obuf[4][16][72];    // L3 out tile
    int t = threadIdx.x, lane = t & 63, wave = t >> 6;
    int y = blockIdx.y;
    int n0 = blockIdx.x * 64 + wave * 16;
    const float* bias = y ? b2l : b2m;
    const unsigned int* w2 = wf2 + (size_t)y * 2 * 8 * 64 * 4;
    const unsigned int* w3 = wf3 + (size_t)y * 4 * 4 * 64 * 4;

    f32x4 acc2[8];
#pragma unroll
    for (int c = 0; c < 8; c++) acc2[c] = (f32x4)(0.f);
    int arow = n0 + (lane & 15);
    bool aok = arow < N;
#pragma unroll
    for (int s = 0; s < 2; s++) {
        U4B af; af.u = make_uint4(0u, 0u, 0u, 0u);
        if (aok) {
            uint2 u = *(const uint2*)((const unsigned char*)hB8 +
                        (size_t)arow * 128 + y * 64 + s * 32 + (lane >> 4) * 8);
            f8_to_bf2(u.x, af.u.x, af.u.y);
            f8_to_bf2(u.y, af.u.z, af.u.w);
        }
#pragma unroll
        for (int c = 0; c < 8; c++) {
            U4B wb;
            wb.u = *(const uint4*)&w2[((size_t)(s * 8 + c) * 64 + lane) * 4];
            acc2[c] = __builtin_amdgcn_mfma_f32_16x16x32_bf16(af.b, wb.b, acc2[c], 0, 0, 0);
        }
    }
#pragma unroll
    for (int c = 0; c < 8; c++) {
        int col = c * 16 + (lane & 15);
        float bv = bias[col];
#pragma unroll
        for (int r = 0; r < 4; r++) {
            int row = (lane >> 4) * 4 + r;
            float v = fmaxf(acc2[c][r] * (1.f / 32.f) + bv, 0.f);
            hbuf[wave][row][col] = f2bf(v);
        }
    }
    // wave-local LDS write->read: same-wave DS ops are in-order; no block barrier needed

    f32x4 acc3[4];
#pragma unroll
    for (int c = 0; c < 4; c++) acc3[c] = (f32x4)(0.f);
#pragma unroll
    for (int s = 0; s < 4; s++) {
        U4B af;
        af.u = *(const uint4*)&hbuf[wave][lane & 15][s * 32 + (lane >> 4) * 8];
#pragma unroll
        for (int c = 0; c < 4; c++) {
            U4B wb;
            wb.u = *(const uint4*)&w3[((size_t)(s * 4 + c) * 64 + lane) * 4];
            acc3[c] = __builtin_amdgcn_mfma_f32_16x16x32_bf16(af.b, wb.b, acc3[c], 0, 0, 0);
        }
    }
#pragma unroll
    for (int c = 0; c < 4; c++) {
        int col = c * 16 + (lane & 15);
#pragma unroll
        for (int r = 0; r < 4; r++) {
            int row = (lane >> 4) * 4 + r;
            int n = n0 + row;
            float v = acc3[c][r] * dinv[min(n, N - 1)];
            obuf[wave][row][col] = f2bf(v);
        }
    }
    __syncthreads();
    for (int i = t; i < 64 * 8; i += 256) {   // F=64 -> 8 chunks/row
        int row = i / 8;
        int f0 = (i % 8) * 8;
        int n = blockIdx.x * 64 + row;
        if (n >= N) continue;
        const unsigned short* bp = &obuf[row >> 4][row & 15][f0];
        uint2 a = *(const uint2*)bp;
        uint2 b = *(const uint2*)(bp + 4);
        float e0 = __uint_as_float(a.x << 16), e1 = __uint_as_float(a.x & 0xFFFF0000u);
        float e2 = __uint_as_float(a.y << 16), e3 = __uint_as_float(a.y & 0xFFFF0000u);
        float e4 = __uint_as_float(b.x << 16), e5 = __uint_as_float(b.x & 0xFFFF0000u);
        float e6 = __uint_as_float(b.y << 16), e7 = __uint_as_float(b.y & 0xFFFF0000u);
        unsigned int r0 = 0, r1 = 0;
        r0 = __builtin_amdgcn_cvt_pk_fp8_f32(e0 * 32.f, e1 * 32.f, r0, false);
        r0 = __builtin_amdgcn_cvt_pk_fp8_f32(e2 * 32.f, e3 * 32.f, r0, true);
        r1 = __builtin_amdgcn_cvt_pk_fp8_f32(e4 * 32.f, e5 * 32.f, r1, false);
        r1 = __builtin_amdgcn_cvt_pk_fp8_f32(e6 * 32.f, e7 * 32.f, r1, true);
        *(uint2*)((unsigned char*)hD8 + (size_t)n * 128 + y * 64 + f0) = make_uint2(r0, r1);
    }
}

// parallel pooled sum: 4 waves/block, each wave reduces 16 rows (run-detected on sorted batch)
__global__ __launch_bounds__(256) void pool128(const unsigned int* __restrict__ h,
                                               const int* __restrict__ batch,
                                               float* __restrict__ sums, int n) {
    int t = threadIdx.x, lane = t & 63, wave = t >> 6;
    int r0 = blockIdx.x * 64 + wave * 16;
    if (r0 >= n) return;
    int r1 = min(r0 + 16, n);
    int cur = batch[r0];
    float a0 = 0.f, a1 = 0.f;
    for (int i = r0; i < r1; i++) {
        int b = batch[i];
        if (b != cur) {
            atomicAdd(&sums[cur * 128 + 2 * lane], a0);
            atomicAdd(&sums[cur * 128 + 2 * lane + 1], a1);
            a0 = a1 = 0.f; cur = b;
        }
        unsigned int u = h[(size_t)i * 64 + lane];
        a0 += __uint_as_float(u << 16);
        a1 += __uint_as_float(u & 0xFFFF0000u);
    }
    atomicAdd(&sums[cur * 128 + 2 * lane], a0);
    atomicAdd(&sums[cur * 128 + 2 * lane + 1], a1);
}

// finalize pool + zwi fused: 16 blocks x 128 threads
__global__ void finalize_zwi(const float* __restrict__ sums, const int* __restrict__ bcnt,
                             const float* __restrict__ nm_wi, const float* __restrict__ nm_bi,
                             const float* __restrict__ em_wi, const float* __restrict__ em_bi,
                             float* __restrict__ out, float* __restrict__ zwi_nm,
                             float* __restrict__ zwi_em) {
    __shared__ float zs[64];
    int b = blockIdx.x, t = threadIdx.x;
    float c = fmaxf((float)bcnt[b], 1.f);
    float v = sums[b * 128 + t] / c;
    if (t < 64) { out[OUT_MU + b * 64 + t] = v; zs[t] = v; }
    else out[OUT_LG + b * 64 + (t - 64)] = v;
    __syncthreads();
    float an = nm_bi[t], ae = em_bi[t];
    for (int k = 0; k < 64; k++) {
        float zv = zs[k];
        an += zv * nm_wi[k * 128 + t];
        ae += zv * em_wi[k * 128 + t];
    }
    zwi_nm[b * 128 + t] = an;
    zwi_em[b * 128 + t] = ae;
}

#define D3_ROWS 32

// decoder3: layer1+LN -> LDS; heads/edges as 128-len LDS dots (heads pre-composed)
__global__ __launch_bounds__(256) void decoder3(
    const float* __restrict__ zwi_nm, const float* __restrict__ zwi_em,
    const float* __restrict__ nm_wi, const float* __restrict__ em_wi,
    const float* __restrict__ nm_g, const float* __restrict__ nm_be,
    const float* __restrict__ em_g, const float* __restrict__ em_be,
    const float* __restrict__ wtn, const float* __restrict__ bcn,
    const float* __restrict__ wte, const float* __restrict__ em_bo,
    const float* __restrict__ pos_all,
    float* __restrict__ out) {
    __shared__ float sn[D3_ROWS][132];
    __shared__ float se[D3_ROWS][132];
    __shared__ float Wn[8][132];
    __shared__ float We[8][132];
    int t = threadIdx.x;
    int lane = t & 63, wave = t >> 6;
    int rowBase = blockIdx.x * D3_ROWS;
    int b = rowBase >> 12;
    int row0 = rowBase + wave * 8;

    for (int i = t; i < 1024; i += 256) {
        Wn[i >> 7][i & 127] = wtn[i];
        We[i >> 7][i & 127] = wte[i];
    }

    int f0 = lane, f1 = lane + 64;
    float zn0 = zwi_nm[b * 128 + f0], zn1 = zwi_nm[b * 128 + f1];
    float ze0 = zwi_em[b * 128 + f0], ze1 = zwi_em[b * 128 + f1];
    float wn64_0 = nm_wi[64 * 128 + f0], wn64_1 = nm_wi[64 * 128 + f1];
    float wn65_0 = nm_wi[65 * 128 + f0], wn65_1 = nm_wi[65 * 128 + f1];
    float we64_0 = em_wi[64 * 128 + f0], we64_1 = em_wi[64 * 128 + f1];
    float we65_0 = em_wi[65 * 128 + f0], we65_1 = em_wi[65 * 128 + f1];
    float gn0 = nm_g[f0], gn1 = nm_g[f1], bn0 = nm_be[f0], bn1 = nm_be[f1];
    float ge0 = em_g[f0], ge1 = em_g[f1], be0 = em_be[f0], be1 = em_be[f1];

#pragma unroll
    for (int r = 0; r < 8; r++) {
        int row = row0 + r, i = row & (NMAXC - 1);
        float px = pos_all[i * 2], py = pos_all[i * 2 + 1];
        float a0 = zn0 + px * wn64_0 + py * wn65_0;
        float a1 = zn1 + px * wn64_1 + py * wn65_1;
        float e0 = ze0 + px * we64_0 + py * we65_0;
        float e1 = ze1 + px * we64_1 + py * we65_1;
        float sm = a0 + a1, sq = a0 * a0 + a1 * a1;
        float sme = e0 + e1, sqe = e0 * e0 + e1 * e1;
#pragma unroll
        for (int d = 1; d < 64; d <<= 1) {
            sm += __shfl_xor(sm, d); sq += __shfl_xor(sq, d);
            sme += __shfl_xor(sme, d); sqe += __shfl_xor(sqe, d);
        }
        float mean = sm * (1.f / 128.f);
        float var = sq * (1.f / 128.f) - mean * mean;
        float rstd = rsqrtf(var + 1e-5f);
        int rl = wave * 8 + r;
        sn[rl][f0] = fmaxf((a0 - mean) * rstd * gn0 + bn0, 0.f);
        sn[rl][f1] = fmaxf((a1 - mean) * rstd * gn1 + bn1, 0.f);
        float meane = sme * (1.f / 128.f);
        float vare = sqe * (1.f / 128.f) - meane * meane;
        float rstde = rsqrtf(vare + 1e-5f);
        se[rl][f0] = fmaxf((e0 - meane) * rstde * ge0 + be0, 0.f);
        se[rl][f1] = fmaxf((e1 - meane) * rstde * ge1 + be1, 0.f);
    }
    __syncthreads();

    int rl = t >> 3, j = t & 7;
    float accn = 0.f, acce = 0.f;
#pragma unroll 8
    for (int k4 = 0; k4 < 128; k4 += 4) {
        float4 sv = *(const float4*)&sn[rl][k4];
        float4 wv = *(const float4*)&Wn[j][k4];
        float4 sev = *(const float4*)&se[rl][k4];
        float4 wev = *(const float4*)&We[j][k4];
        accn += sv.x * wv.x + sv.y * wv.y + sv.z * wv.z + sv.w * wv.w;
        acce += sev.x * wev.x + sev.y * wev.y + sev.z * wev.z + sev.w * wev.w;
    }
    int row = rowBase + rl;
    accn += bcn[j];
    if (j == 0)       out[OUT_NODES + row] = accn;
    else if (j <= 5)  out[OUT_FUEL + (size_t)row * 5 + (j - 1)] = accn;
    else if (j == 6)  out[OUT_ALT + row] = accn;
    else              out[OUT_SLOPE + row] = accn;
    out[OUT_EDGES + (size_t)row * 8 + j] = acce + em_bo[j];
}

extern "C" void kernel_launch(void* const* d_in, const int* in_sizes, int n_in,
                              void* d_out, int out_size, void* d_ws, size_t ws_size,
                              hipStream_t stream) {
    const float* x    = (const float*)d_in[0];
    const int* edge   = (const int*)d_in[1];
    const int* batch  = (const int*)d_in[2];
    const float* w1m = (const float*)d_in[3];  const float* b1m = (const float*)d_in[4];
    const float* w2m = (const float*)d_in[5];  const float* b2m = (const float*)d_in[6];
    const float* w3m = (const float*)d_in[7];  const float* b3m = (const float*)d_in[8];
    const float* w1l = (const float*)d_in[9];  const float* b1l = (const float*)d_in[10];
    const float* w2l = (const float*)d_in[11]; const float* b2l = (const float*)d_in[12];
    const float* w3l = (const float*)d_in[13]; const float* b3l = (const float*)d_in[14];
    const float* nm_wi = (const float*)d_in[15]; const float* nm_bi = (const float*)d_in[16];
    const float* nm_g  = (const float*)d_in[17]; const float* nm_be = (const float*)d_in[18];
    const float* nm_wo = (const float*)d_in[19]; const float* nm_bo = (const float*)d_in[20];
    const float* ex_w = (const float*)d_in[21]; const float* ex_b = (const float*)d_in[22];
    const float* fu_w = (const float*)d_in[23]; const float* fu_b = (const float*)d_in[24];
    const float* al_w = (const float*)d_in[25]; const float* al_b = (const float*)d_in[26];
    const float* sl_w = (const float*)d_in[27]; const float* sl_b = (const float*)d_in[28];
    const float* em_wi = (const float*)d_in[29]; const float* em_bi = (const float*)d_in[30];
    const float* em_g  = (const float*)d_in[31]; const float* em_be = (const float*)d_in[32];
    const float* em_wo = (const float*)d_in[33]; const float* em_bo = (const float*)d_in[34];
    const float* pos_all = (const float*)d_in[35];
    float* out = (float*)d_out;

    char* p = (char*)d_ws;
    auto alloc = [&](size_t bytes) -> void* {
        void* r = (void*)p;
        p += ((bytes + 255) / 256) * 256;
        return r;
    };
    int2* oc      = (int2*)alloc((size_t)N_NODES * 8);
    float* dinv   = (float*)alloc((size_t)N_NODES * 4);
    int* bcnt     = (int*)alloc(BATCH_B * 4);
    float* sums   = (float*)alloc(BATCH_B * 128 * 4);
    float* zwi_nm = (float*)alloc(BATCH_B * 128 * 4);
    float* zwi_em = (float*)alloc(BATCH_B * 128 * 4);
    float* bcat1  = (float*)alloc(128 * 4);
    float* bcat3  = (float*)alloc(128 * 4);
    float* wtn    = (float*)alloc(8 * 128 * 4);
    float* bcn    = (float*)alloc(8 * 4);
    float* wte    = (float*)alloc(8 * 128 * 4);
    unsigned int* wf1 = (unsigned int*)alloc((size_t)8 * 64 * 4 * 4);
    unsigned int* wf2 = (unsigned int*)alloc((size_t)32 * 64 * 4 * 4);
    unsigned int* wf3 = (unsigned int*)alloc((size_t)32 * 64 * 4 * 4);
    int* hist     = (int*)alloc((size_t)NBINS * NSB * 4);
    int* total    = (int*)alloc((size_t)NBINS * 4);
    int* base     = (int*)alloc((size_t)(NBINS + 1) * 4);
    unsigned int* sorted = (unsigned int*)alloc((size_t)N_EDGESC * 4);
    int* adj      = (int*)alloc((size_t)(N_EDGESC + NBINS * BIN_PAD + 256) * 4);
    unsigned int* xs8 = (unsigned int*)alloc((size_t)N_NODES * 8 * 4);
    unsigned short* agg0b = (unsigned short*)alloc((size_t)N_NODES * 32 * 2);
    unsigned int* hA8 = (unsigned int*)alloc((size_t)N_NODES * 32 * 4);
    unsigned int* hB8 = (unsigned int*)alloc((size_t)N_NODES * 32 * 4);
    unsigned short* final128 = (unsigned short*)alloc((size_t)N_NODES * 128 * 2);
    unsigned int* hD8 = hA8;  // hA8 dead after agg #1

    const int* srcp = edge;
    const int* dstp = edge + N_EDGESC;

    hipMemsetAsync(sums, 0, (size_t)BATCH_B * 128 * 4, stream);

    mega_prep<<<82, 256, 0, stream>>>(batch, w1m, w1l, b1m, b1l, b3m, b3l,
                                      w2m, w2l, w3m, w3l, nm_wo, nm_bo,
                                      ex_w, ex_b, fu_w, fu_b, al_w, al_b, sl_w, sl_b,
                                      em_wo, bcnt, bcat1, bcat3, wtn, bcn, wte,
                                      wf1, wf2, wf3);

    // ---- CSR build: atomic-free counting sort -> compact aligned CSR (+fused prescale) ----
    histA<<<NSB, 1024, 0, stream>>>(dstp, hist);
    scanB<<<NBINS, NSB, 0, stream>>>(hist, total);
    scanC<<<1, 512, 0, stream>>>(total, base);
    scatterD<<<NSB, 1024, 0, stream>>>(srcp, dstp, hist, base, sorted);
    csr_compact<<<NBINS, 256, 0, stream>>>(sorted, base, x, adj, oc, dinv, xs8, N_NODES);

    // agg0 = S x  (shared by both branches), fp8 table -> bf16 out
    agg_s32<<<(N_NODES + 31) / 32, 256, 0, stream>>>(xs8, oc, adj, dinv, agg0b, N_NODES);

    const int GB = (N_NODES + 63) / 64;  // 1563 row blocks

    // L1 (fused mu|lg): hA8 = fp8x32( dinv * relu(agg0 @ [w1m|w1l] + bcat1) )  [MFMA]
    mfma_conv1<<<GB, 256, 0, stream>>>(agg0b, wf1, bcat1, dinv, hA8, N_NODES);

    // agg #1: hB8 = fp8x32( [S mu1 | S lg1] )
    agg128<false, true><<<(N_NODES + 7) / 8, 256, 0, stream>>>(
        hA8, oc, adj, dinv, nullptr, hB8, N_NODES);

    // fused L2+L3: hD8 = fp8x32( dinv * ( relu(hB8@w2 + b2) @ w3 ) )  [MFMA, LDS mid]
    conv23<<<dim3(GB, 2), 256, 0, stream>>>(hB8, wf2, wf3, b2m, b2l, dinv, hD8, N_NODES);

    // agg #2: final = relu(dinv*(sum) + bcat3) = [mu3|lg3]  -> bf16 [n][128]
    agg128<true, false><<<(N_NODES + 7) / 8, 256, 0, stream>>>(
        hD8, oc, adj, dinv, bcat3, final128, N_NODES);

    pool128<<<GB, 256, 0, stream>>>((const unsigned int*)final128, batch, sums, N_NODES);
    finalize_zwi<<<BATCH_B, 128, 0, stream>>>(sums, bcnt, nm_wi, nm_bi, em_wi, em_bi,
                                              out, zwi_nm, zwi_em);

    decoder3<<<BATCH_B * NMAXC / D3_ROWS, 256, 0, stream>>>(
        zwi_nm, zwi_em, nm_wi, em_wi, nm_g, nm_be, em_g, em_be,
        wtn, bcn, wte, em_bo, pos_all, out);
}

// Round 16
// 257.057 us; speedup vs baseline: 1.0811x; 1.0006x over previous
//
#include <hip/hip_runtime.h>
#include <hip/hip_bf16.h>

#define N_NODES 100000
#define N_EDGESC 1600000
#define BATCH_B 16
#define NMAXC 4096
#define LATC 64
#define NBINS 391   // ceil(100000/256): 256 nodes per bin
#define NSB 256     // sort blocks
#define EPB ((N_EDGESC + NSB - 1) / NSB)  // 6250 edges per sort block
#define BIN_PAD 768 // worst-case per-bin alignment padding (256 nodes x 3)

// output layout offsets (flat f32)
#define OUT_NODES 0
#define OUT_EDGES 65536
#define OUT_FUEL  589824
#define OUT_ALT   917504
#define OUT_SLOPE 983040
#define OUT_MU    1048576
#define OUT_LG    1049600

typedef float f32x2 __attribute__((ext_vector_type(2)));
typedef float f32x4 __attribute__((ext_vector_type(4)));
typedef short bf16x8 __attribute__((ext_vector_type(8)));
union U4B { uint4 u; bf16x8 b; };

__device__ __forceinline__ unsigned short f2bf(float f) {
    unsigned int u = __float_as_uint(f);
    return (unsigned short)((u + 0x7FFFu + ((u >> 16) & 1u)) >> 16);  // RNE
}
__device__ __forceinline__ float bf2f(unsigned short h) {
    return __uint_as_float(((unsigned int)h) << 16);
}
__device__ __forceinline__ void f8acc(unsigned int u, float& a0, float& a1, float& a2, float& a3) {
    f32x2 lo = __builtin_amdgcn_cvt_pk_f32_fp8(u, false);
    f32x2 hi = __builtin_amdgcn_cvt_pk_f32_fp8(u, true);
    a0 += lo[0]; a1 += lo[1]; a2 += hi[0]; a3 += hi[1];
}
// decode 4 fp8 -> bf16x2 pair packed in 2 uints
__device__ __forceinline__ void f8_to_bf2(unsigned int u, unsigned int& q0, unsigned int& q1) {
    f32x2 lo = __builtin_amdgcn_cvt_pk_f32_fp8(u, false);
    f32x2 hi = __builtin_amdgcn_cvt_pk_f32_fp8(u, true);
    q0 = (unsigned int)f2bf(lo[0]) | ((unsigned int)f2bf(lo[1]) << 16);
    q1 = (unsigned int)f2bf(hi[0]) | ((unsigned int)f2bf(hi[1]) << 16);
}

// device helper: pack one B-fragment quad from f32 weight matrix
__device__ __forceinline__ void wfrag_write(const float* W, int F, int col, int k0,
                                            unsigned int* dst) {
    unsigned int q[4];
#pragma unroll
    for (int jj = 0; jj < 4; jj++) {
        float lo = W[(size_t)(k0 + 2 * jj) * F + col];
        float hi = W[(size_t)(k0 + 2 * jj + 1) * F + col];
        q[jj] = (unsigned int)f2bf(lo) | ((unsigned int)f2bf(hi) << 16);
    }
    *(uint4*)dst = make_uint4(q[0], q[1], q[2], q[3]);
}

// ---- fused mega-prep + histA: blocks 0..81 prep, 82..(82+NSB-1) histogram ----
__global__ __launch_bounds__(1024) void prep_hist(
    const int* __restrict__ batch, const int* __restrict__ dst,
    const float* __restrict__ w1m, const float* __restrict__ w1l,
    const float* __restrict__ b1m, const float* __restrict__ b1l,
    const float* __restrict__ b3m, const float* __restrict__ b3l,
    const float* __restrict__ w2m, const float* __restrict__ w2l,
    const float* __restrict__ w3m, const float* __restrict__ w3l,
    const float* __restrict__ nm_wo, const float* __restrict__ nm_bo,
    const float* __restrict__ ex_w, const float* __restrict__ ex_b,
    const float* __restrict__ fu_w, const float* __restrict__ fu_b,
    const float* __restrict__ al_w, const float* __restrict__ al_b,
    const float* __restrict__ sl_w, const float* __restrict__ sl_b,
    const float* __restrict__ em_wo,
    int* __restrict__ bcnt, float* __restrict__ bcat1,
    float* __restrict__ bcat3, float* __restrict__ wtn,
    float* __restrict__ bcn, float* __restrict__ wte,
    unsigned int* __restrict__ wf1, unsigned int* __restrict__ wf2,
    unsigned int* __restrict__ wf3, int* __restrict__ hist) {
    int blk = blockIdx.x, t = threadIdx.x;
    if (blk >= 82) {  // histogram part
        __shared__ int h[NBINS];
        int b = blk - 82;
        for (int i = t; i < NBINS; i += 1024) h[i] = 0;
        __syncthreads();
        int e0 = b * EPB, e1 = min(e0 + EPB, N_EDGESC);
        for (int i = e0 + t; i < e1; i += 1024)
            atomicAdd(&h[dst[i] >> 8], 1);
        __syncthreads();
        for (int i = t; i < NBINS; i += 1024) hist[i * NSB + b] = h[i];
        return;
    }
    if (t >= 256) return;
    if (blk == 0) {
        if (t < 128) bcat1[t] = (t < 64) ? b1m[t] : b1l[t - 64];
        else { int f = t - 128; bcat3[f] = (f < 64) ? b3m[f] : b3l[f - 64]; }
        if (t < BATCH_B) {
            int b = t;
            int lo = 0, hi = N_NODES;
            while (lo < hi) { int mid = (lo + hi) >> 1; if (batch[mid] < b) lo = mid + 1; else hi = mid; }
            int start = lo;
            lo = 0; hi = N_NODES;
            while (lo < hi) { int mid = (lo + hi) >> 1; if (batch[mid] <= b) lo = mid + 1; else hi = mid; }
            bcnt[b] = lo - start;
        }
    } else if (blk <= 9) {
        int idx = (blk - 1) * 256 + t;
        if (idx < 1024) {
            int j = idx >> 7, k = idx & 127;
            float s = 0.f;
            for (int m = 0; m < 128; m++) {
                float w = (j == 0) ? ex_w[m] : (j <= 5) ? fu_w[m * 5 + (j - 1)]
                         : (j == 6) ? al_w[m] : sl_w[m];
                s += nm_wo[k * 128 + m] * w;
            }
            wtn[j * 128 + k] = s;
        } else if (idx < 2048) {
            int i2 = idx - 1024;
            int j = i2 >> 7, k = i2 & 127;
            wte[j * 128 + k] = em_wo[k * 8 + j];
        } else if (idx < 2056) {
            int j = idx - 2048;
            float s = (j == 0) ? ex_b[0] : (j <= 5) ? fu_b[j - 1] : (j == 6) ? al_b[0] : sl_b[0];
            for (int m = 0; m < 128; m++) {
                float w = (j == 0) ? ex_w[m] : (j <= 5) ? fu_w[m * 5 + (j - 1)]
                         : (j == 6) ? al_w[m] : sl_w[m];
                s += nm_bo[m] * w;
            }
            bcn[j] = s;
        }
    } else if (blk <= 17) {     // wf1: K=32, F=128 concat [w1m|w1l]
        if (t < 64) {
            int c = blk - 10;
            int col = c * 16 + (t & 15);
            int k0 = (t >> 4) * 8;
            unsigned int q[4];
#pragma unroll
            for (int jj = 0; jj < 4; jj++) {
                int ka = k0 + 2 * jj, kb = ka + 1;
                float lo = (col < 64) ? w1m[ka * 64 + col] : w1l[ka * 64 + col - 64];
                float hi = (col < 64) ? w1m[kb * 64 + col] : w1l[kb * 64 + col - 64];
                q[jj] = (unsigned int)f2bf(lo) | ((unsigned int)f2bf(hi) << 16);
            }
            *(uint4*)&wf1[((size_t)c * 64 + t) * 4] = make_uint4(q[0], q[1], q[2], q[3]);
        }
    } else if (blk <= 49) {     // wf2: K=64 (S=2), F=128 (C=8), y in {0,1}
        if (t < 64) {
            int bc = blk - 18;
            int c = bc % 8, s = (bc / 8) % 2, y = bc / 16;
            const float* W = y ? w2l : w2m;
            wfrag_write(W, 128, c * 16 + (t & 15), s * 32 + (t >> 4) * 8,
                        &wf2[((size_t)bc * 64 + t) * 4]);
        }
    } else {                    // wf3: K=128 (S=4), F=64 (C=4), y in {0,1}
        if (t < 64) {
            int bc = blk - 50;
            int c = bc % 4, s = (bc / 4) % 4, y = bc / 16;
            const float* W = y ? w3l : w3m;
            wfrag_write(W, 64, c * 16 + (t & 15), s * 32 + (t >> 4) * 8,
                        &wf3[((size_t)bc * 64 + t) * 4]);
        }
    }
}

__global__ void scanB(int* __restrict__ hist, int* __restrict__ total) {
    __shared__ int sh[NSB];
    int j = blockIdx.x, t = threadIdx.x;  // 256 threads
    int v = hist[j * NSB + t];
    sh[t] = v; __syncthreads();
    for (int off = 1; off < NSB; off <<= 1) {
        int u = (t >= off) ? sh[t - off] : 0; __syncthreads();
        sh[t] += u; __syncthreads();
    }
    hist[j * NSB + t] = sh[t] - v;
    if (t == NSB - 1) total[j] = sh[t];
}

__global__ void scanC(const int* __restrict__ total, int* __restrict__ base) {
    __shared__ int sh[512];
    int t = threadIdx.x;
    int v = (t < NBINS) ? total[t] : 0;
    sh[t] = v; __syncthreads();
    for (int off = 1; off < 512; off <<= 1) {
        int u = (t >= off) ? sh[t - off] : 0; __syncthreads();
        sh[t] += u; __syncthreads();
    }
    if (t < NBINS) base[t] = sh[t] - v;
    if (t == NBINS - 1) base[NBINS] = sh[t];
}

__global__ __launch_bounds__(1024) void scatterD(const int* __restrict__ src, const int* __restrict__ dst,
                                                 const int* __restrict__ hist, const int* __restrict__ base,
                                                 unsigned int* __restrict__ sorted) {
    __shared__ int w0[NBINS];
    __shared__ int lc[NBINS];
    int b = blockIdx.x, t = threadIdx.x;
    for (int i = t; i < NBINS; i += 1024) {
        w0[i] = base[i] + hist[i * NSB + b];
        lc[i] = 0;
    }
    __syncthreads();
    int e0 = b * EPB, e1 = min(e0 + EPB, N_EDGESC);
    for (int i = e0 + t; i < e1; i += 1024) {
        int d = dst[i], s = src[i];
        int j = d >> 8;
        int r = atomicAdd(&lc[j], 1);
        sorted[w0[j] + r] = ((unsigned int)s << 8) | (d & 255);
    }
}

// compact CSR with 16B-aligned per-node lists + fused fp8 prescale of x
__global__ void csr_compact(const unsigned int* __restrict__ sorted, const int* __restrict__ base,
                            const float* __restrict__ x,
                            int* __restrict__ adj, int2* __restrict__ oc,
                            float* __restrict__ dinv, unsigned int* __restrict__ xs8, int N) {
    __shared__ int lc[256];
    __shared__ int cur[256];
    __shared__ int so4[256];
    int j = blockIdx.x, t = threadIdx.x;
    lc[t] = 0; cur[t] = 0;
    __syncthreads();
    int e0 = base[j], e1 = base[j + 1];
    for (int i = e0 + t; i < e1; i += 256)
        atomicAdd(&lc[sorted[i] & 255], 1);
    __syncthreads();
    int c4 = (lc[t] + 3) & ~3;   // align each list to 4 entries (16B)
    so4[t] = c4;
    __syncthreads();
    for (int off = 1; off < 256; off <<= 1) {
        int u = (t >= off) ? so4[t - off] : 0; __syncthreads();
        so4[t] += u; __syncthreads();
    }
    int mybase = base[j] + j * BIN_PAD + so4[t] - c4;  // exclusive, aligned
    __syncthreads();
    so4[t] = mybase;
    __syncthreads();
    for (int i = e0 + t; i < e1; i += 256) {
        unsigned int pk = sorted[i];
        int d = pk & 255;
        int r = atomicAdd(&cur[d], 1);
        adj[so4[d] + r] = (int)(pk >> 8);
    }
    int n = j * 256 + t;
    if (n < N) {
        int c = lc[t];
        oc[n] = make_int2(so4[t], c);
        float dv = rsqrtf((float)(c + 1));  // +1 = self loop
        dinv[n] = dv;
        float ds = dv * 64.f;
        const float* xr = &x[(size_t)n * 32];
        unsigned int q[8];
#pragma unroll
        for (int jj = 0; jj < 8; jj++) {
            float4 v = *(const float4*)&xr[jj * 4];
            unsigned int r8 = 0;
            r8 = __builtin_amdgcn_cvt_pk_fp8_f32(v.x * ds, v.y * ds, r8, false);
            r8 = __builtin_amdgcn_cvt_pk_fp8_f32(v.z * ds, v.w * ds, r8, true);
            q[jj] = r8;
        }
        *(uint4*)&xs8[(size_t)n * 8] = make_uint4(q[0], q[1], q[2], q[3]);
        *(uint4*)&xs8[(size_t)n * 8 + 4] = make_uint4(q[4], q[5], q[6], q[7]);
    }
}

// ---- fused agg0 + L1 conv: aggregate 64 nodes into LDS (bf16), then MFMA conv ----
// out hA8 = fp8x32( dinv * relu( (S x) @ [w1m|w1l] + bcat1 ) )
__global__ __launch_bounds__(256) void agg_conv1(
    const unsigned int* __restrict__ xs8, const int2* __restrict__ oc,
    const int* __restrict__ adj, const float* __restrict__ dinv,
    const unsigned int* __restrict__ wfrag, const float* __restrict__ bias,
    unsigned int* __restrict__ outv, int N) {
    __shared__ unsigned short albuf[64][36];    // agg result (pad 36 -> bank rotation)
    __shared__ unsigned short buf[4][16][132];  // output pack staging
    int t = threadIdx.x, lane = t & 63, wave = t >> 6;
    int nb0 = blockIdx.x * 64;

    // phase 1: aggregate 64 nodes, 8 lanes (32 feats) per node, 2 nodes per thread-slot
#pragma unroll
    for (int half = 0; half < 2; half++) {
        int nl = half * 32 + (t >> 3);
        int f = t & 7;
        int n = nb0 + nl;
        ushort4 o = make_ushort4(0, 0, 0, 0);
        if (n < N) {
            float s0 = 0.f, s1 = 0.f, s2 = 0.f, s3 = 0.f;
            f8acc(xs8[(size_t)n * 8 + f], s0, s1, s2, s3);
            int2 h = oc[n];
            int e = h.x, e1 = h.x + h.y;
            for (; e + 8 <= e1; e += 8) {
                int4 ia = *(const int4*)&adj[e];
                int4 ib = *(const int4*)&adj[e + 4];
                unsigned int u0 = xs8[(size_t)ia.x * 8 + f];
                unsigned int u1 = xs8[(size_t)ia.y * 8 + f];
                unsigned int u2 = xs8[(size_t)ia.z * 8 + f];
                unsigned int u3 = xs8[(size_t)ia.w * 8 + f];
                unsigned int u4 = xs8[(size_t)ib.x * 8 + f];
                unsigned int u5 = xs8[(size_t)ib.y * 8 + f];
                unsigned int u6 = xs8[(size_t)ib.z * 8 + f];
                unsigned int u7 = xs8[(size_t)ib.w * 8 + f];
                f8acc(u0, s0, s1, s2, s3); f8acc(u1, s0, s1, s2, s3);
                f8acc(u2, s0, s1, s2, s3); f8acc(u3, s0, s1, s2, s3);
                f8acc(u4, s0, s1, s2, s3); f8acc(u5, s0, s1, s2, s3);
                f8acc(u6, s0, s1, s2, s3); f8acc(u7, s0, s1, s2, s3);
            }
            if (e + 4 <= e1) {
                int4 ia = *(const int4*)&adj[e];
                unsigned int u0 = xs8[(size_t)ia.x * 8 + f];
                unsigned int u1 = xs8[(size_t)ia.y * 8 + f];
                unsigned int u2 = xs8[(size_t)ia.z * 8 + f];
                unsigned int u3 = xs8[(size_t)ia.w * 8 + f];
                f8acc(u0, s0, s1, s2, s3); f8acc(u1, s0, s1, s2, s3);
                f8acc(u2, s0, s1, s2, s3); f8acc(u3, s0, s1, s2, s3);
                e += 4;
            }
            for (; e < e1; e++) f8acc(xs8[(size_t)adj[e] * 8 + f], s0, s1, s2, s3);
            float d = dinv[n] * (1.f / 64.f);
            o.x = f2bf(s0 * d); o.y = f2bf(s1 * d); o.z = f2bf(s2 * d); o.w = f2bf(s3 * d);
        }
        *(ushort4*)&albuf[nl][f * 4] = o;
    }
    __syncthreads();

    // phase 2: MFMA conv (K=32, F=128), A fragments from LDS
    int n0 = nb0 + wave * 16;
    f32x4 acc[8];
#pragma unroll
    for (int c = 0; c < 8; c++) acc[c] = (f32x4)(0.f);
    int rl = wave * 16 + (lane & 15);
    U4B af;
    af.u = *(const uint4*)&albuf[rl][(lane >> 4) * 8];
#pragma unroll
    for (int c = 0; c < 8; c++) {
        U4B wb;
        wb.u = *(const uint4*)&wfrag[((size_t)c * 64 + lane) * 4];
        acc[c] = __builtin_amdgcn_mfma_f32_16x16x32_bf16(af.b, wb.b, acc[c], 0, 0, 0);
    }
#pragma unroll
    for (int c = 0; c < 8; c++) {
        int col = c * 16 + (lane & 15);
        float bv = bias[col];
#pragma unroll
        for (int r = 0; r < 4; r++) {
            int row = (lane >> 4) * 4 + r;
            int n = n0 + row;
            float v = fmaxf(acc[c][r] + bv, 0.f) * dinv[min(n, N - 1)];
            buf[wave][row][col] = f2bf(v);
        }
    }
    __syncthreads();
    for (int i = t; i < 64 * 16; i += 256) {   // CPR = 128/8 = 16
        int row = i / 16;
        int f0 = (i % 16) * 8;
        int n = nb0 + row;
        if (n >= N) continue;
        const unsigned short* bp = &buf[row >> 4][row & 15][f0];
        uint2 a = *(const uint2*)bp;
        uint2 b = *(const uint2*)(bp + 4);
        float e0 = __uint_as_float(a.x << 16), e1 = __uint_as_float(a.x & 0xFFFF0000u);
        float e2 = __uint_as_float(a.y << 16), e3 = __uint_as_float(a.y & 0xFFFF0000u);
        float e4 = __uint_as_float(b.x << 16), e5 = __uint_as_float(b.x & 0xFFFF0000u);
        float e6 = __uint_as_float(b.y << 16), e7 = __uint_as_float(b.y & 0xFFFF0000u);
        unsigned int r0 = 0, r1 = 0;
        r0 = __builtin_amdgcn_cvt_pk_fp8_f32(e0 * 32.f, e1 * 32.f, r0, false);
        r0 = __builtin_amdgcn_cvt_pk_fp8_f32(e2 * 32.f, e3 * 32.f, r0, true);
        r1 = __builtin_amdgcn_cvt_pk_fp8_f32(e4 * 32.f, e5 * 32.f, r1, false);
        r1 = __builtin_amdgcn_cvt_pk_fp8_f32(e6 * 32.f, e7 * 32.f, r1, true);
        *(uint2*)((unsigned char*)outv + (size_t)n * 128 + f0) = make_uint2(r0, r1);
    }
}

// 128-dim fp8-table aggregation (table pre-scaled x32); 8 nodes/block, 32 lanes/node
template <bool BIASRELU, bool OUT8>
__global__ void agg128(const unsigned int* __restrict__ tbl, const int2* __restrict__ oc,
                       const int* __restrict__ adj, const float* __restrict__ dinv,
                       const float* __restrict__ bias, void* __restrict__ outv, int N) {
    int t = threadIdx.x;
    int sub = t >> 5, f = t & 31;
    int n = blockIdx.x * 8 + sub;
    if (n >= N) return;
    float s0 = 0.f, s1 = 0.f, s2 = 0.f, s3 = 0.f;
    f8acc(tbl[(size_t)n * 32 + f], s0, s1, s2, s3);
    int2 h = oc[n];
    int e = h.x, e1 = h.x + h.y;
    for (; e + 8 <= e1; e += 8) {
        int4 ia = *(const int4*)&adj[e];
        int4 ib = *(const int4*)&adj[e + 4];
        unsigned int u0 = tbl[(size_t)ia.x * 32 + f];
        unsigned int u1 = tbl[(size_t)ia.y * 32 + f];
        unsigned int u2 = tbl[(size_t)ia.z * 32 + f];
        unsigned int u3 = tbl[(size_t)ia.w * 32 + f];
        unsigned int u4 = tbl[(size_t)ib.x * 32 + f];
        unsigned int u5 = tbl[(size_t)ib.y * 32 + f];
        unsigned int u6 = tbl[(size_t)ib.z * 32 + f];
        unsigned int u7 = tbl[(size_t)ib.w * 32 + f];
        f8acc(u0, s0, s1, s2, s3); f8acc(u1, s0, s1, s2, s3);
        f8acc(u2, s0, s1, s2, s3); f8acc(u3, s0, s1, s2, s3);
        f8acc(u4, s0, s1, s2, s3); f8acc(u5, s0, s1, s2, s3);
        f8acc(u6, s0, s1, s2, s3); f8acc(u7, s0, s1, s2, s3);
    }
    if (e + 4 <= e1) {
        int4 ia = *(const int4*)&adj[e];
        unsigned int u0 = tbl[(size_t)ia.x * 32 + f];
        unsigned int u1 = tbl[(size_t)ia.y * 32 + f];
        unsigned int u2 = tbl[(size_t)ia.z * 32 + f];
        unsigned int u3 = tbl[(size_t)ia.w * 32 + f];
        f8acc(u0, s0, s1, s2, s3); f8acc(u1, s0, s1, s2, s3);
        f8acc(u2, s0, s1, s2, s3); f8acc(u3, s0, s1, s2, s3);
        e += 4;
    }
    for (; e < e1; e++) f8acc(tbl[(size_t)adj[e] * 32 + f], s0, s1, s2, s3);
    float d = dinv[n] * (1.f / 32.f);
    float v0 = s0 * d, v1 = s1 * d, v2 = s2 * d, v3 = s3 * d;
    if (BIASRELU) {
        float4 bv = *(const float4*)&bias[4 * f];
        v0 = fmaxf(v0 + bv.x, 0.f); v1 = fmaxf(v1 + bv.y, 0.f);
        v2 = fmaxf(v2 + bv.z, 0.f); v3 = fmaxf(v3 + bv.w, 0.f);
    }
    if (OUT8) {
        unsigned int r = 0;
        r = __builtin_amdgcn_cvt_pk_fp8_f32(v0 * 32.f, v1 * 32.f, r, false);
        r = __builtin_amdgcn_cvt_pk_fp8_f32(v2 * 32.f, v3 * 32.f, r, true);
        ((unsigned int*)outv)[(size_t)n * 32 + f] = r;
    } else {
        ushort4 u;
        u.x = f2bf(v0); u.y = f2bf(v1); u.z = f2bf(v2); u.w = f2bf(v3);
        *(ushort4*)&((unsigned short*)outv)[(size_t)n * 128 + 4 * f] = u;
    }
}

// ---- fused L2+L3 conv: hB8 -> (L2, LDS) -> (L3) -> hD8. Per branch y; 64 rows/block.
__global__ __launch_bounds__(256) void conv23(
    const unsigned int* __restrict__ hB8, const unsigned int* __restrict__ wf2,
    const unsigned int* __restrict__ wf3, const float* __restrict__ b2m,
    const float* __restrict__ b2l, const float* __restrict__ dinv,
    unsigned int* __restrict__ hD8, int N) {
    __shared__ unsigned short hbuf[4][16][136];   // L2 out tile (wave-local)
    __shared__ unsigned short obuf[4][16][72];    // L3 out tile
    int t = threadIdx.x, lane = t & 63, wave = t >> 6;
    int y = blockIdx.y;
    int n0 = blockIdx.x * 64 + wave * 16;
    const float* bias = y ? b2l : b2m;
    const unsigned int* w2 = wf2 + (size_t)y * 2 * 8 * 64 * 4;
    const unsigned int* w3 = wf3 + (size_t)y * 4 * 4 * 64 * 4;

    f32x4 acc2[8];
#pragma unroll
    for (int c = 0; c < 8; c++) acc2[c] = (f32x4)(0.f);
    int arow = n0 + (lane & 15);
    bool aok = arow < N;
#pragma unroll
    for (int s = 0; s < 2; s++) {
        U4B af; af.u = make_uint4(0u, 0u, 0u, 0u);
        if (aok) {
            uint2 u = *(const uint2*)((const unsigned char*)hB8 +
                        (size_t)arow * 128 + y * 64 + s * 32 + (lane >> 4) * 8);
            f8_to_bf2(u.x, af.u.x, af.u.y);
            f8_to_bf2(u.y, af.u.z, af.u.w);
        }
#pragma unroll
        for (int c = 0; c < 8; c++) {
            U4B wb;
            wb.u = *(const uint4*)&w2[((size_t)(s * 8 + c) * 64 + lane) * 4];
            acc2[c] = __builtin_amdgcn_mfma_f32_16x16x32_bf16(af.b, wb.b, acc2[c], 0, 0, 0);
        }
    }
#pragma unroll
    for (int c = 0; c < 8; c++) {
        int col = c * 16 + (lane & 15);
        float bv = bias[col];
#pragma unroll
        for (int r = 0; r < 4; r++) {
            int row = (lane >> 4) * 4 + r;
            float v = fmaxf(acc2[c][r] * (1.f / 32.f) + bv, 0.f);
            hbuf[wave][row][col] = f2bf(v);
        }
    }
    // wave-local LDS write->read: same-wave DS ops are in-order; no block barrier needed

    f32x4 acc3[4];
#pragma unroll
    for (int c = 0; c < 4; c++) acc3[c] = (f32x4)(0.f);
#pragma unroll
    for (int s = 0; s < 4; s++) {
        U4B af;
        af.u = *(const uint4*)&hbuf[wave][lane & 15][s * 32 + (lane >> 4) * 8];
#pragma unroll
        for (int c = 0; c < 4; c++) {
            U4B wb;
            wb.u = *(const uint4*)&w3[((size_t)(s * 4 + c) * 64 + lane) * 4];
            acc3[c] = __builtin_amdgcn_mfma_f32_16x16x32_bf16(af.b, wb.b, acc3[c], 0, 0, 0);
        }
    }
#pragma unroll
    for (int c = 0; c < 4; c++) {
        int col = c * 16 + (lane & 15);
#pragma unroll
        for (int r = 0; r < 4; r++) {
            int row = (lane >> 4) * 4 + r;
            int n = n0 + row;
            float v = acc3[c][r] * dinv[min(n, N - 1)];
            obuf[wave][row][col] = f2bf(v);
        }
    }
    __syncthreads();
    for (int i = t; i < 64 * 8; i += 256) {   // F=64 -> 8 chunks/row
        int row = i / 8;
        int f0 = (i % 8) * 8;
        int n = blockIdx.x * 64 + row;
        if (n >= N) continue;
        const unsigned short* bp = &obuf[row >> 4][row & 15][f0];
        uint2 a = *(const uint2*)bp;
        uint2 b = *(const uint2*)(bp + 4);
        float e0 = __uint_as_float(a.x << 16), e1 = __uint_as_float(a.x & 0xFFFF0000u);
        float e2 = __uint_as_float(a.y << 16), e3 = __uint_as_float(a.y & 0xFFFF0000u);
        float e4 = __uint_as_float(b.x << 16), e5 = __uint_as_float(b.x & 0xFFFF0000u);
        float e6 = __uint_as_float(b.y << 16), e7 = __uint_as_float(b.y & 0xFFFF0000u);
        unsigned int r0 = 0, r1 = 0;
        r0 = __builtin_amdgcn_cvt_pk_fp8_f32(e0 * 32.f, e1 * 32.f, r0, false);
        r0 = __builtin_amdgcn_cvt_pk_fp8_f32(e2 * 32.f, e3 * 32.f, r0, true);
        r1 = __builtin_amdgcn_cvt_pk_fp8_f32(e4 * 32.f, e5 * 32.f, r1, false);
        r1 = __builtin_amdgcn_cvt_pk_fp8_f32(e6 * 32.f, e7 * 32.f, r1, true);
        *(uint2*)((unsigned char*)hD8 + (size_t)n * 128 + y * 64 + f0) = make_uint2(r0, r1);
    }
}

// parallel pooled sum: 4 waves/block, each wave reduces 16 rows (run-detected on sorted batch)
__global__ __launch_bounds__(256) void pool128(const unsigned int* __restrict__ h,
                                               const int* __restrict__ batch,
                                               float* __restrict__ sums, int n) {
    int t = threadIdx.x, lane = t & 63, wave = t >> 6;
    int r0 = blockIdx.x * 64 + wave * 16;
    if (r0 >= n) return;
    int r1 = min(r0 + 16, n);
    int cur = batch[r0];
    float a0 = 0.f, a1 = 0.f;
    for (int i = r0; i < r1; i++) {
        int b = batch[i];
        if (b != cur) {
            atomicAdd(&sums[cur * 128 + 2 * lane], a0);
            atomicAdd(&sums[cur * 128 + 2 * lane + 1], a1);
            a0 = a1 = 0.f; cur = b;
        }
        unsigned int u = h[(size_t)i * 64 + lane];
        a0 += __uint_as_float(u << 16);
        a1 += __uint_as_float(u & 0xFFFF0000u);
    }
    atomicAdd(&sums[cur * 128 + 2 * lane], a0);
    atomicAdd(&sums[cur * 128 + 2 * lane + 1], a1);
}

// finalize pool + zwi fused: 16 blocks x 128 threads
__global__ void finalize_zwi(const float* __restrict__ sums, const int* __restrict__ bcnt,
                             const float* __restrict__ nm_wi, const float* __restrict__ nm_bi,
                             const float* __restrict__ em_wi, const float* __restrict__ em_bi,
                             float* __restrict__ out, float* __restrict__ zwi_nm,
                             float* __restrict__ zwi_em) {
    __shared__ float zs[64];
    int b = blockIdx.x, t = threadIdx.x;
    float c = fmaxf((float)bcnt[b], 1.f);
    float v = sums[b * 128 + t] / c;
    if (t < 64) { out[OUT_MU + b * 64 + t] = v; zs[t] = v; }
    else out[OUT_LG + b * 64 + (t - 64)] = v;
    __syncthreads();
    float an = nm_bi[t], ae = em_bi[t];
    for (int k = 0; k < 64; k++) {
        float zv = zs[k];
        an += zv * nm_wi[k * 128 + t];
        ae += zv * em_wi[k * 128 + t];
    }
    zwi_nm[b * 128 + t] = an;
    zwi_em[b * 128 + t] = ae;
}

#define D3_ROWS 32

// decoder3: layer1+LN -> LDS; heads/edges as 128-len LDS dots (heads pre-composed)
__global__ __launch_bounds__(256) void decoder3(
    const float* __restrict__ zwi_nm, const float* __restrict__ zwi_em,
    const float* __restrict__ nm_wi, const float* __restrict__ em_wi,
    const float* __restrict__ nm_g, const float* __restrict__ nm_be,
    const float* __restrict__ em_g, const float* __restrict__ em_be,
    const float* __restrict__ wtn, const float* __restrict__ bcn,
    const float* __restrict__ wte, const float* __restrict__ em_bo,
    const float* __restrict__ pos_all,
    float* __restrict__ out) {
    __shared__ float sn[D3_ROWS][132];
    __shared__ float se[D3_ROWS][132];
    __shared__ float Wn[8][132];
    __shared__ float We[8][132];
    int t = threadIdx.x;
    int lane = t & 63, wave = t >> 6;
    int rowBase = blockIdx.x * D3_ROWS;
    int b = rowBase >> 12;
    int row0 = rowBase + wave * 8;

    for (int i = t; i < 1024; i += 256) {
        Wn[i >> 7][i & 127] = wtn[i];
        We[i >> 7][i & 127] = wte[i];
    }

    int f0 = lane, f1 = lane + 64;
    float zn0 = zwi_nm[b * 128 + f0], zn1 = zwi_nm[b * 128 + f1];
    float ze0 = zwi_em[b * 128 + f0], ze1 = zwi_em[b * 128 + f1];
    float wn64_0 = nm_wi[64 * 128 + f0], wn64_1 = nm_wi[64 * 128 + f1];
    float wn65_0 = nm_wi[65 * 128 + f0], wn65_1 = nm_wi[65 * 128 + f1];
    float we64_0 = em_wi[64 * 128 + f0], we64_1 = em_wi[64 * 128 + f1];
    float we65_0 = em_wi[65 * 128 + f0], we65_1 = em_wi[65 * 128 + f1];
    float gn0 = nm_g[f0], gn1 = nm_g[f1], bn0 = nm_be[f0], bn1 = nm_be[f1];
    float ge0 = em_g[f0], ge1 = em_g[f1], be0 = em_be[f0], be1 = em_be[f1];

#pragma unroll
    for (int r = 0; r < 8; r++) {
        int row = row0 + r, i = row & (NMAXC - 1);
        float px = pos_all[i * 2], py = pos_all[i * 2 + 1];
        float a0 = zn0 + px * wn64_0 + py * wn65_0;
        float a1 = zn1 + px * wn64_1 + py * wn65_1;
        float e0 = ze0 + px * we64_0 + py * we65_0;
        float e1 = ze1 + px * we64_1 + py * we65_1;
        float sm = a0 + a1, sq = a0 * a0 + a1 * a1;
        float sme = e0 + e1, sqe = e0 * e0 + e1 * e1;
#pragma unroll
        for (int d = 1; d < 64; d <<= 1) {
            sm += __shfl_xor(sm, d); sq += __shfl_xor(sq, d);
            sme += __shfl_xor(sme, d); sqe += __shfl_xor(sqe, d);
        }
        float mean = sm * (1.f / 128.f);
        float var = sq * (1.f / 128.f) - mean * mean;
        float rstd = rsqrtf(var + 1e-5f);
        int rl = wave * 8 + r;
        sn[rl][f0] = fmaxf((a0 - mean) * rstd * gn0 + bn0, 0.f);
        sn[rl][f1] = fmaxf((a1 - mean) * rstd * gn1 + bn1, 0.f);
        float meane = sme * (1.f / 128.f);
        float vare = sqe * (1.f / 128.f) - meane * meane;
        float rstde = rsqrtf(vare + 1e-5f);
        se[rl][f0] = fmaxf((e0 - meane) * rstde * ge0 + be0, 0.f);
        se[rl][f1] = fmaxf((e1 - meane) * rstde * ge1 + be1, 0.f);
    }
    __syncthreads();

    int rl = t >> 3, j = t & 7;
    float accn = 0.f, acce = 0.f;
#pragma unroll 8
    for (int k4 = 0; k4 < 128; k4 += 4) {
        float4 sv = *(const float4*)&sn[rl][k4];
        float4 wv = *(const float4*)&Wn[j][k4];
        float4 sev = *(const float4*)&se[rl][k4];
        float4 wev = *(const float4*)&We[j][k4];
        accn += sv.x * wv.x + sv.y * wv.y + sv.z * wv.z + sv.w * wv.w;
        acce += sev.x * wev.x + sev.y * wev.y + sev.z * wev.z + sev.w * wev.w;
    }
    int row = rowBase + rl;
    accn += bcn[j];
    if (j == 0)       out[OUT_NODES + row] = accn;
    else if (j <= 5)  out[OUT_FUEL + (size_t)row * 5 + (j - 1)] = accn;
    else if (j == 6)  out[OUT_ALT + row] = accn;
    else              out[OUT_SLOPE + row] = accn;
    out[OUT_EDGES + (size_t)row * 8 + j] = acce + em_bo[j];
}

extern "C" void kernel_launch(void* const* d_in, const int* in_sizes, int n_in,
                              void* d_out, int out_size, void* d_ws, size_t ws_size,
                              hipStream_t stream) {
    const float* x    = (const float*)d_in[0];
    const int* edge   = (const int*)d_in[1];
    const int* batch  = (const int*)d_in[2];
    const float* w1m = (const float*)d_in[3];  const float* b1m = (const float*)d_in[4];
    const float* w2m = (const float*)d_in[5];  const float* b2m = (const float*)d_in[6];
    const float* w3m = (const float*)d_in[7];  const float* b3m = (const float*)d_in[8];
    const float* w1l = (const float*)d_in[9];  const float* b1l = (const float*)d_in[10];
    const float* w2l = (const float*)d_in[11]; const float* b2l = (const float*)d_in[12];
    const float* w3l = (const float*)d_in[13]; const float* b3l = (const float*)d_in[14];
    const float* nm_wi = (const float*)d_in[15]; const float* nm_bi = (const float*)d_in[16];
    const float* nm_g  = (const float*)d_in[17]; const float* nm_be = (const float*)d_in[18];
    const float* nm_wo = (const float*)d_in[19]; const float* nm_bo = (const float*)d_in[20];
    const float* ex_w = (const float*)d_in[21]; const float* ex_b = (const float*)d_in[22];
    const float* fu_w = (const float*)d_in[23]; const float* fu_b = (const float*)d_in[24];
    const float* al_w = (const float*)d_in[25]; const float* al_b = (const float*)d_in[26];
    const float* sl_w = (const float*)d_in[27]; const float* sl_b = (const float*)d_in[28];
    const float* em_wi = (const float*)d_in[29]; const float* em_bi = (const float*)d_in[30];
    const float* em_g  = (const float*)d_in[31]; const float* em_be = (const float*)d_in[32];
    const float* em_wo = (const float*)d_in[33]; const float* em_bo = (const float*)d_in[34];
    const float* pos_all = (const float*)d_in[35];
    float* out = (float*)d_out;

    char* p = (char*)d_ws;
    auto alloc = [&](size_t bytes) -> void* {
        void* r = (void*)p;
        p += ((bytes + 255) / 256) * 256;
        return r;
    };
    int2* oc      = (int2*)alloc((size_t)N_NODES * 8);
    float* dinv   = (float*)alloc((size_t)N_NODES * 4);
    int* bcnt     = (int*)alloc(BATCH_B * 4);
    float* sums   = (float*)alloc(BATCH_B * 128 * 4);
    float* zwi_nm = (float*)alloc(BATCH_B * 128 * 4);
    float* zwi_em = (float*)alloc(BATCH_B * 128 * 4);
    float* bcat1  = (float*)alloc(128 * 4);
    float* bcat3  = (float*)alloc(128 * 4);
    float* wtn    = (float*)alloc(8 * 128 * 4);
    float* bcn    = (float*)alloc(8 * 4);
    float* wte    = (float*)alloc(8 * 128 * 4);
    unsigned int* wf1 = (unsigned int*)alloc((size_t)8 * 64 * 4 * 4);
    unsigned int* wf2 = (unsigned int*)alloc((size_t)32 * 64 * 4 * 4);
    unsigned int* wf3 = (unsigned int*)alloc((size_t)32 * 64 * 4 * 4);
    int* hist     = (int*)alloc((size_t)NBINS * NSB * 4);
    int* total    = (int*)alloc((size_t)NBINS * 4);
    int* base     = (int*)alloc((size_t)(NBINS + 1) * 4);
    unsigned int* sorted = (unsigned int*)alloc((size_t)N_EDGESC * 4);
    int* adj      = (int*)alloc((size_t)(N_EDGESC + NBINS * BIN_PAD + 256) * 4);
    unsigned int* xs8 = (unsigned int*)alloc((size_t)N_NODES * 8 * 4);
    unsigned int* hA8 = (unsigned int*)alloc((size_t)N_NODES * 32 * 4);
    unsigned int* hB8 = (unsigned int*)alloc((size_t)N_NODES * 32 * 4);
    unsigned short* final128 = (unsigned short*)alloc((size_t)N_NODES * 128 * 2);
    unsigned int* hD8 = hA8;  // hA8 dead after agg #1

    const int* srcp = edge;
    const int* dstp = edge + N_EDGESC;

    hipMemsetAsync(sums, 0, (size_t)BATCH_B * 128 * 4, stream);

    // prep (blocks 0..81) + edge histogram (blocks 82..337), one kernel
    prep_hist<<<82 + NSB, 1024, 0, stream>>>(batch, dstp, w1m, w1l, b1m, b1l, b3m, b3l,
                                             w2m, w2l, w3m, w3l, nm_wo, nm_bo,
                                             ex_w, ex_b, fu_w, fu_b, al_w, al_b, sl_w, sl_b,
                                             em_wo, bcnt, bcat1, bcat3, wtn, bcn, wte,
                                             wf1, wf2, wf3, hist);

    scanB<<<NBINS, NSB, 0, stream>>>(hist, total);
    scanC<<<1, 512, 0, stream>>>(total, base);
    scatterD<<<NSB, 1024, 0, stream>>>(srcp, dstp, hist, base, sorted);
    csr_compact<<<NBINS, 256, 0, stream>>>(sorted, base, x, adj, oc, dinv, xs8, N_NODES);

    const int GB = (N_NODES + 63) / 64;  // 1563 row blocks

    // fused agg0 + L1 conv: hA8 = fp8x32( dinv * relu((S x) @ [w1m|w1l] + bcat1) )
    agg_conv1<<<GB, 256, 0, stream>>>(xs8, oc, adj, dinv, wf1, bcat1, hA8, N_NODES);

    // agg #1: hB8 = fp8x32( [S mu1 | S lg1] )
    agg128<false, true><<<(N_NODES + 7) / 8, 256, 0, stream>>>(
        hA8, oc, adj, dinv, nullptr, hB8, N_NODES);

    // fused L2+L3: hD8 = fp8x32( dinv * ( relu(hB8@w2 + b2) @ w3 ) )  [MFMA, LDS mid]
    conv23<<<dim3(GB, 2), 256, 0, stream>>>(hB8, wf2, wf3, b2m, b2l, dinv, hD8, N_NODES);

    // agg #2: final = relu(dinv*(sum) + bcat3) = [mu3|lg3]  -> bf16 [n][128]
    agg128<true, false><<<(N_NODES + 7) / 8, 256, 0, stream>>>(
        hD8, oc, adj, dinv, bcat3, final128, N_NODES);

    pool128<<<GB, 256, 0, stream>>>((const unsigned int*)final128, batch, sums, N_NODES);
    finalize_zwi<<<BATCH_B, 128, 0, stream>>>(sums, bcnt, nm_wi, nm_bi, em_wi, em_bi,
                                              out, zwi_nm, zwi_em);

    decoder3<<<BATCH_B * NMAXC / D3_ROWS, 256, 0, stream>>>(
        zwi_nm, zwi_em, nm_wi, em_wi, nm_g, nm_be, em_g, em_be,
        wtn, bcn, wte, em_bo, pos_all, out);
}